// Round 9
// baseline (2866.601 us; speedup 1.0000x reference)
//
#include <hip/hip_runtime.h>
#include <hip/hip_bf16.h>
#include <math.h>

// Model dims
#define BB     16
#define LL     197
#define DD     384
#define DEPTH  24
#define DI     768
#define DSN    16
#define DTR    24
#define NC     1000
#define TT     (BB*LL)      // 3152 tokens
#define NPATCH 196
#define EPSV   1e-5f

// chunked scan config: 12 chunks of 17 tokens (wave = chunk in k_scan)
#define NCHUNK 12
#define CH     17
#define XZROWS 19          // conv tile: rows t0-3 .. t0+15

typedef __attribute__((ext_vector_type(8))) short short8;
typedef __attribute__((ext_vector_type(4))) short short4v;
typedef __attribute__((ext_vector_type(4))) float f32x4;

__device__ __forceinline__ short f2bf(float f) {
  union { float f; unsigned u; } v; v.f = f;
  unsigned u = v.u + 0x7fffu + ((v.u >> 16) & 1u);
  return (short)(u >> 16);
}

// async global->LDS, 16B per lane; lds dest is wave-uniform base + lane*16
__device__ __forceinline__ void gload16(const short* g, const short* l) {
  __builtin_amdgcn_global_load_lds(
      (const __attribute__((address_space(1))) unsigned int*)g,
      (__attribute__((address_space(3))) unsigned int*)l, 16, 0, 0);
}
__device__ __forceinline__ void gload16f(const float* g, const float* l) {
  __builtin_amdgcn_global_load_lds(
      (const __attribute__((address_space(1))) unsigned int*)g,
      (__attribute__((address_space(3))) unsigned int*)l, 16, 0, 0);
}

// ---------------------------------------------------------------------------
// fp32 -> bf16 bulk convert, 4 segments in one dispatch (weights, once/call)
// ---------------------------------------------------------------------------
__global__ __launch_bounds__(256) void k_cvt4(const float* __restrict__ s0, short* __restrict__ d0, int n0,
                                              const float* __restrict__ s1, short* __restrict__ d1, int n1,
                                              const float* __restrict__ s2, short* __restrict__ d2, int n2,
                                              const float* __restrict__ s3, short* __restrict__ d3, int n3,
                                              int b0, int b1, int b2) {
  int blk = blockIdx.x;
  const float* src; short* dst; int n; int lb;
  if (blk < b0)      { src = s0; dst = d0; n = n0; lb = blk; }
  else if (blk < b1) { src = s1; dst = d1; n = n1; lb = blk - b0; }
  else if (blk < b2) { src = s2; dst = d2; n = n2; lb = blk - b1; }
  else               { src = s3; dst = d3; n = n3; lb = blk - b2; }
  int i = (lb * 256 + threadIdx.x) * 4;
  if (i + 3 < n) {
    float4 v = *(const float4*)&src[i];
    short4v o = {f2bf(v.x), f2bf(v.y), f2bf(v.z), f2bf(v.w)};
    *(short4v*)&dst[i] = o;
  } else {
    for (int j = 0; i + j < n && j < 4; j++) dst[i + j] = f2bf(src[i + j]);
  }
}

// ---------------------------------------------------------------------------
// init: write cls token rows of res (res = h0; patches filled by k_patch)
// ---------------------------------------------------------------------------
__global__ __launch_bounds__(256) void k_init(const float* __restrict__ cls,
                                              const float* __restrict__ pos,
                                              float* __restrict__ res) {
  int i = blockIdx.x * 256 + threadIdx.x;
  if (i < BB * DD) {
    int b = i / DD, d = i % DD;
    res[(size_t)(b * LL) * DD + d] = cls[d] + pos[d];
  }
}

// ---------------------------------------------------------------------------
// patch embed: bf16 MFMA GEMM with fused im2col (runs once; fp32 inputs)
// writes res (= h0) directly.
// ---------------------------------------------------------------------------
__global__ __launch_bounds__(256) void k_patch(const float* __restrict__ x,
                                               const float* __restrict__ pw,
                                               const float* __restrict__ pb,
                                               const float* __restrict__ pos,
                                               float* __restrict__ res) {
  __shared__ short sA[64 * 40];
  __shared__ short sB[64 * 40];
  const int tid = threadIdx.x;
  const int m0 = blockIdx.x * 64, n0 = blockIdx.y * 64;
  const int srow = tid >> 2;
  const int skq = (tid & 3) * 8;
  const int lane = tid & 63, w = tid >> 6;
  const int wm = (w >> 1) * 32, wn = (w & 1) * 32;
  const int fr = lane & 15;
  const int fk = (lane >> 4) * 8;
  f32x4 acc[2][2] = {};
  const int m = m0 + srow;
  const int b = m / NPATCH;
  const int p = m % NPATCH;
  const int ph = p / 14, pwi = p % 14;
  const float* Wrow = pw + (size_t)(n0 + srow) * 768 + skq;
  for (int k0 = 0; k0 < 768; k0 += 32) {
    int k = k0 + skq;
    int c = k >> 8, rr = (k >> 4) & 15, kw = k & 15;
    const float* xrow = &x[(size_t)(((b * 3 + c) * 224) + (ph * 16 + rr)) * 224 +
                           (pwi * 16 + kw)];
    float4 a0 = *(const float4*)&xrow[0];
    float4 a1 = *(const float4*)&xrow[4];
    float4 b0 = *(const float4*)&Wrow[k0];
    float4 b1 = *(const float4*)&Wrow[k0 + 4];
    short8 av = {f2bf(a0.x), f2bf(a0.y), f2bf(a0.z), f2bf(a0.w),
                 f2bf(a1.x), f2bf(a1.y), f2bf(a1.z), f2bf(a1.w)};
    short8 bv = {f2bf(b0.x), f2bf(b0.y), f2bf(b0.z), f2bf(b0.w),
                 f2bf(b1.x), f2bf(b1.y), f2bf(b1.z), f2bf(b1.w)};
    *(short8*)&sA[srow * 40 + skq] = av;
    *(short8*)&sB[srow * 40 + skq] = bv;
    __syncthreads();
    short8 af0 = *(const short8*)&sA[(wm + fr) * 40 + fk];
    short8 af1 = *(const short8*)&sA[(wm + 16 + fr) * 40 + fk];
    short8 bf0 = *(const short8*)&sB[(wn + fr) * 40 + fk];
    short8 bf1 = *(const short8*)&sB[(wn + 16 + fr) * 40 + fk];
    acc[0][0] = __builtin_amdgcn_mfma_f32_16x16x32_bf16(af0, bf0, acc[0][0], 0, 0, 0);
    acc[0][1] = __builtin_amdgcn_mfma_f32_16x16x32_bf16(af0, bf1, acc[0][1], 0, 0, 0);
    acc[1][0] = __builtin_amdgcn_mfma_f32_16x16x32_bf16(af1, bf0, acc[1][0], 0, 0, 0);
    acc[1][1] = __builtin_amdgcn_mfma_f32_16x16x32_bf16(af1, bf1, acc[1][1], 0, 0, 0);
    __syncthreads();
  }
#pragma unroll
  for (int i = 0; i < 2; i++)
#pragma unroll
    for (int j = 0; j < 2; j++)
#pragma unroll
      for (int q = 0; q < 4; q++) {
        int mm = m0 + wm + i * 16 + (lane >> 4) * 4 + q;
        int nn = n0 + wn + j * 16 + (lane & 15);
        int b2 = mm / NPATCH, pp = mm % NPATCH;
        int tok = b2 * LL + 1 + pp;
        res[(size_t)tok * DD + nn] = acc[i][j][q] + pb[nn] + pos[(size_t)(1 + pp) * DD + nn];
      }
}

// ---------------------------------------------------------------------------
// m97-style 128x128 bf16 GEMM: C[M,N] = A[M,K] * W[N,K]^T. (in_proj)
// ---------------------------------------------------------------------------
__global__ __launch_bounds__(256) void k_gemm128(const short* __restrict__ A, int lda,
                                                 const short* __restrict__ W, int ldb,
                                                 float* __restrict__ C, int ldc,
                                                 int M, int N, int K) {
  __shared__ short sA[128 * 32];
  __shared__ short sB[128 * 32];
  const int tid = threadIdx.x;
  const int lane = tid & 63, w = tid >> 6;
  const int m0 = blockIdx.x * 128, n0 = blockIdx.y * 128;
  const int wm = (w >> 1) * 64, wn = (w & 1) * 64;
  const int fr = lane & 15;
  const int fk = (lane >> 4) * 8;
  const int q0 = w * 2, q1 = w * 2 + 1;
  const int sr0 = q0 * 16 + (lane >> 2);
  const int sr1 = q1 * 16 + (lane >> 2);
  const int scol = (lane & 3) * 8;
  f32x4 acc[4][4] = {};
  const short* Ab0 = A + (size_t)(m0 + sr0) * lda + scol;
  const short* Ab1 = A + (size_t)(m0 + sr1) * lda + scol;
  const short* Bb0 = W + (size_t)(n0 + sr0) * ldb + scol;
  const short* Bb1 = W + (size_t)(n0 + sr1) * ldb + scol;
  for (int k0 = 0; k0 < K; k0 += 32) {
    gload16(Ab0 + k0, &sA[q0 * 512]);
    gload16(Ab1 + k0, &sA[q1 * 512]);
    gload16(Bb0 + k0, &sB[q0 * 512]);
    gload16(Bb1 + k0, &sB[q1 * 512]);
    __syncthreads();
    short8 af[4], bf[4];
#pragma unroll
    for (int i = 0; i < 4; i++) {
      af[i] = *(const short8*)&sA[(wm + i * 16 + fr) * 32 + fk];
      bf[i] = *(const short8*)&sB[(wn + i * 16 + fr) * 32 + fk];
    }
#pragma unroll
    for (int i = 0; i < 4; i++)
#pragma unroll
      for (int j = 0; j < 4; j++)
        acc[i][j] = __builtin_amdgcn_mfma_f32_16x16x32_bf16(af[i], bf[j], acc[i][j], 0, 0, 0);
    __syncthreads();
  }
#pragma unroll
  for (int i = 0; i < 4; i++)
#pragma unroll
    for (int j = 0; j < 4; j++)
#pragma unroll
      for (int q = 0; q < 4; q++) {
        int mm = m0 + wm + i * 16 + (lane >> 4) * 4 + q;
        int nn = n0 + wn + j * 16 + fr;
        if (mm < M) C[(size_t)mm * ldc + nn] = acc[i][j][q];
      }
}

// ---------------------------------------------------------------------------
// 64x64 bf16 GEMM, out_proj with residual accumulate: res += y @ Wout^T
// ---------------------------------------------------------------------------
__global__ __launch_bounds__(256) void k_gemm64(const short* __restrict__ A, int lda,
                                                const short* __restrict__ W, int ldb,
                                                float* __restrict__ C, int ldc,
                                                int M, int N, int K) {
  __shared__ short sA[64 * 32];
  __shared__ short sB[64 * 32];
  const int tid = threadIdx.x;
  const int lane = tid & 63, w = tid >> 6;
  const int m0 = blockIdx.x * 64, n0 = blockIdx.y * 64;
  const int wm = (w >> 1) * 32, wn = (w & 1) * 32;
  const int fr = lane & 15;
  const int fk = (lane >> 4) * 8;
  const int srow = w * 16 + (lane >> 2);
  const int scol = (lane & 3) * 8;
  f32x4 acc[2][2] = {};
  const short* Ab = A + (size_t)(m0 + srow) * lda + scol;
  const short* Bb = W + (size_t)(n0 + srow) * ldb + scol;
  for (int k0 = 0; k0 < K; k0 += 32) {
    gload16(Ab + k0, &sA[w * 512]);
    gload16(Bb + k0, &sB[w * 512]);
    __syncthreads();
    short8 af0 = *(const short8*)&sA[(wm + fr) * 32 + fk];
    short8 af1 = *(const short8*)&sA[(wm + 16 + fr) * 32 + fk];
    short8 bf0 = *(const short8*)&sB[(wn + fr) * 32 + fk];
    short8 bf1 = *(const short8*)&sB[(wn + 16 + fr) * 32 + fk];
    acc[0][0] = __builtin_amdgcn_mfma_f32_16x16x32_bf16(af0, bf0, acc[0][0], 0, 0, 0);
    acc[0][1] = __builtin_amdgcn_mfma_f32_16x16x32_bf16(af0, bf1, acc[0][1], 0, 0, 0);
    acc[1][0] = __builtin_amdgcn_mfma_f32_16x16x32_bf16(af1, bf0, acc[1][0], 0, 0, 0);
    acc[1][1] = __builtin_amdgcn_mfma_f32_16x16x32_bf16(af1, bf1, acc[1][1], 0, 0, 0);
    __syncthreads();
  }
#pragma unroll
  for (int i = 0; i < 2; i++)
#pragma unroll
    for (int j = 0; j < 2; j++)
#pragma unroll
      for (int q = 0; q < 4; q++) {
        int mm = m0 + wm + i * 16 + (lane >> 4) * 4 + q;
        int nn = n0 + wn + j * 16 + fr;
        if (mm < M) C[(size_t)mm * ldc + nn] += acc[i][j][q];
      }
}

// ---------------------------------------------------------------------------
// FUSED conv + x_proj + dt_proj with ASYNC LDS staging (unchanged from R8).
// ---------------------------------------------------------------------------
__global__ __launch_bounds__(256, 1) void k_cxd3(const float* __restrict__ xz,
                                                 const float* __restrict__ wc,
                                                 const float* __restrict__ bc,
                                                 const short* __restrict__ wx,
                                                 const short* __restrict__ wdt,
                                                 const float* __restrict__ dbias,
                                                 float* __restrict__ xc,
                                                 float* __restrict__ dbl,
                                                 float* __restrict__ dtb) {
  __shared__ float sXZ[XZROWS * 768];   // 58368 B
  __shared__ float sWC[768 * 4];        // 12288 B
  __shared__ float sBC[768];            //  3072 B
  __shared__ short sXC[16 * 776];       // 24832 B
  __shared__ short sDT[16 * 40];        //  1280 B
  const int tid = threadIdx.x;
  const int t0 = blockIdx.x * 16;
  const int lane = tid & 63, wv = tid >> 6;
  // ---- phase 0: async staging (DMA; one drain at the barrier)
  for (int r = wv; r < XZROWS; r += 4) {
    int srow = t0 - 3 + r; if (srow < 0) srow = 0;
    const float* src = xz + (size_t)srow * (2 * DI);
#pragma unroll
    for (int s = 0; s < 3; s++)
      gload16f(src + s * 256 + lane * 4, &sXZ[r * 768 + s * 256]);
  }
#pragma unroll
  for (int s = 0; s < 3; s++) {
    int off = (wv * 3 + s) * 256;
    gload16f(wc + off + lane * 4, &sWC[off]);
  }
  if (wv < 3) {
    int off = wv * 256;
    gload16f(bc + off + lane * 4, &sBC[off]);
  }
  __syncthreads();   // compiler drains vmcnt before barrier
  // ---- phase 1: conv + SiLU from LDS (16 tokens x 192 groups; 12/thread)
#pragma unroll
  for (int it = 0; it < 12; it++) {
    int g = tid + it * 256;
    int tl = g / 192, eg = g % 192;
    int e = eg * 4;
    int t = t0 + tl;
    int l = t % LL;
    const float* baseL = &sXZ[(tl + 3) * 768 + e];
    float4 w0 = *(const float4*)&sWC[(e + 0) * 4];
    float4 w1 = *(const float4*)&sWC[(e + 1) * 4];
    float4 w2 = *(const float4*)&sWC[(e + 2) * 4];
    float4 w3 = *(const float4*)&sWC[(e + 3) * 4];
    float4 acc = *(const float4*)&sBC[e];
    if (l >= 3) {
      float4 xv = *(const float4*)&baseL[-3 * 768];
      acc.x += xv.x * w0.x; acc.y += xv.y * w1.x; acc.z += xv.z * w2.x; acc.w += xv.w * w3.x;
    }
    if (l >= 2) {
      float4 xv = *(const float4*)&baseL[-2 * 768];
      acc.x += xv.x * w0.y; acc.y += xv.y * w1.y; acc.z += xv.z * w2.y; acc.w += xv.w * w3.y;
    }
    if (l >= 1) {
      float4 xv = *(const float4*)&baseL[-768];
      acc.x += xv.x * w0.z; acc.y += xv.y * w1.z; acc.z += xv.z * w2.z; acc.w += xv.w * w3.z;
    }
    {
      float4 xv = *(const float4*)&baseL[0];
      acc.x += xv.x * w0.w; acc.y += xv.y * w1.w; acc.z += xv.z * w2.w; acc.w += xv.w * w3.w;
    }
    acc.x = acc.x / (1.f + __expf(-acc.x));
    acc.y = acc.y / (1.f + __expf(-acc.y));
    acc.z = acc.z / (1.f + __expf(-acc.z));
    acc.w = acc.w / (1.f + __expf(-acc.w));
    *(float4*)&xc[(size_t)t * DI + e] = acc;
    short4v ov = {f2bf(acc.x), f2bf(acc.y), f2bf(acc.z), f2bf(acc.w)};
    *(short4v*)&sXC[tl * 776 + e] = ov;
  }
  __syncthreads();
  // ---- phase 2: x_proj (A from sXC, W from L2-hot global, no barriers)
  const int fr = lane & 15;
  const int fk = (lane >> 4) * 8;
  f32x4 acc0 = {}, acc1 = {};
  const short* Wrow = wx + (size_t)(wv * 16 + fr) * DI + fk;
#pragma unroll
  for (int k0 = 0; k0 < DI; k0 += 64) {
    short8 af0 = *(const short8*)&sXC[fr * 776 + k0 + fk];
    short8 bf0 = *(const short8*)&Wrow[k0];
    short8 af1 = *(const short8*)&sXC[fr * 776 + k0 + 32 + fk];
    short8 bf1 = *(const short8*)&Wrow[k0 + 32];
    acc0 = __builtin_amdgcn_mfma_f32_16x16x32_bf16(af0, bf0, acc0, 0, 0, 0);
    acc1 = __builtin_amdgcn_mfma_f32_16x16x32_bf16(af1, bf1, acc1, 0, 0, 0);
  }
  f32x4 accx = acc0 + acc1;
  // ---- phase 3: scatter dbl (cols 24..55) + sDT (cols 0..23, pad 0)
  {
    int nn = wv * 16 + fr;
#pragma unroll
    for (int q = 0; q < 4; q++) {
      int row = (lane >> 4) * 4 + q;
      int t = t0 + row;
      if (nn >= DTR && nn < 56) dbl[(size_t)t * 56 + nn] = accx[q];
      if (wv < 2) sDT[row * 40 + nn] = (nn < DTR) ? f2bf(accx[q]) : (short)0;
    }
  }
  __syncthreads();
  // ---- phase 4: dt_proj (M=16, N=768, K=24 pad 32), W from global
  short8 adt = *(const short8*)&sDT[fr * 40 + fk];
  const int g = lane >> 4;
#pragma unroll
  for (int jj = 0; jj < 12; jj++) {
    int j = wv * 12 + jj;
    short8 bdt = short8{0, 0, 0, 0, 0, 0, 0, 0};
    if (g < 3) bdt = *(const short8*)&wdt[(size_t)(j * 16 + fr) * DTR + g * 8];
    f32x4 p = {};
    p = __builtin_amdgcn_mfma_f32_16x16x32_bf16(adt, bdt, p, 0, 0, 0);
    int nc = j * 16 + fr;
    float bv = dbias[nc];
#pragma unroll
    for (int q = 0; q < 4; q++) {
      int t = t0 + (lane >> 4) * 4 + q;
      float v = p[q] + bv;
      v = (v > 20.f) ? v : __logf(1.f + __expf(v));
      dtb[(size_t)t * DI + nc] = v;
    }
  }
}

// ---------------------------------------------------------------------------
// SINGLE-DISPATCH chunked scan, exp-reduced + prefetched.
// Block = (32-e, b); wave = chunk; carries in LDS; two passes.
//  - dA via powers of p=exp(-dt) when A_log has the arange structure
//    (wave-uniform runtime check; generic 8-expf fallback preserved).
//  - serial loops hand-prefetch step l+1's global loads under step l's VALU.
//  - pass2's first-step loads issue before the LDS carry fold.
// ---------------------------------------------------------------------------
__global__ __launch_bounds__(768) void k_scan(const float* __restrict__ dt,
                                              const float* __restrict__ xc,
                                              const float* __restrict__ xz,
                                              const float* __restrict__ dbl,
                                              const float* __restrict__ Alog,
                                              const float* __restrict__ Dp,
                                              short* __restrict__ ybf) {
  __shared__ float carry[NCHUNK][32][2][17];  // [c][e][nh][0..7 Aprod, 8..15 Hend]
  const int tid = threadIdx.x;
  const int c  = tid >> 6;          // wave index = chunk
  const int nh = (tid >> 5) & 1;
  const int el = tid & 31;
  const int e  = blockIdx.x * 32 + el;
  const int b  = blockIdx.y;
  float4 al0 = *(const float4*)&Alog[(size_t)e * DSN + nh * 8];
  float4 al1 = *(const float4*)&Alog[(size_t)e * DSN + nh * 8 + 4];
  float negA[8] = {-__expf(al0.x), -__expf(al0.y), -__expf(al0.z), -__expf(al0.w),
                   -__expf(al1.x), -__expf(al1.y), -__expf(al1.z), -__expf(al1.w)};
  // A_log arange-structure check: negA[j] ?= -(nh*8+j+1). Wave-uniform.
  bool fastA = true;
#pragma unroll
  for (int j = 0; j < 8; j++) {
    float expect = (float)(nh * 8 + j + 1);
    fastA = fastA && (fabsf(negA[j] + expect) <= 1e-3f * expect);
  }
  fastA = __all(fastA);
  // dA[j] = exp(x * negA[j]); fast path: powers of p = exp(-x)
  auto dAfn = [&](float x, float* dA) {
    if (fastA) {
      float p = __expf(-x);
      float p2 = p * p, p4 = p2 * p2, p8 = p4 * p4;
      float cur = nh ? p8 : 1.f;
#pragma unroll
      for (int j = 0; j < 8; j++) { cur *= p; dA[j] = cur; }
    } else {
#pragma unroll
      for (int j = 0; j < 8; j++) dA[j] = __expf(x * negA[j]);
    }
  };
  const int l0 = c * CH;
  const int l1 = (l0 + CH < LL) ? (l0 + CH) : LL;
  const size_t tbase = (size_t)b * LL;
  // ---- pass 1: local chunk scan (last chunk's carry never consumed)
  if (c < NCHUNK - 1) {
    float h[8] = {};
    float asum = 0.f;
    size_t t = tbase + l0;
    float dtv = dt[t * DI + e];
    float xcv = xc[t * DI + e];
    float4 B0 = *(const float4*)&dbl[t * 56 + DTR + nh * 8];
    float4 B1 = *(const float4*)&dbl[t * 56 + DTR + nh * 8 + 4];
    for (int l = l0; l < l1; l++) {
      float ndt = 0.f, nxc = 0.f;
      float4 nB0 = {}, nB1 = {};
      if (l + 1 < l1) {
        size_t tn = tbase + l + 1;
        ndt = dt[tn * DI + e];
        nxc = xc[tn * DI + e];
        nB0 = *(const float4*)&dbl[tn * 56 + DTR + nh * 8];
        nB1 = *(const float4*)&dbl[tn * 56 + DTR + nh * 8 + 4];
      }
      float dA[8]; dAfn(dtv, dA);
      float dx = dtv * xcv;
      float Bv[8] = {B0.x, B0.y, B0.z, B0.w, B1.x, B1.y, B1.z, B1.w};
#pragma unroll
      for (int j = 0; j < 8; j++)
        h[j] = dA[j] * h[j] + dx * Bv[j];
      asum += dtv;
      dtv = ndt; xcv = nxc; B0 = nB0; B1 = nB1;
    }
    float cA[8]; dAfn(asum, cA);
#pragma unroll
    for (int j = 0; j < 8; j++) {
      carry[c][el][nh][j]     = cA[j];
      carry[c][el][nh][8 + j] = h[j];
    }
  }
  __syncthreads();
  // ---- pass2 first-step loads issue before the fold (latency hides under it)
  size_t tf = tbase + l0;
  float dtv = dt[tf * DI + e];
  float xcv = xc[tf * DI + e];
  float zv  = xz[tf * (2 * DI) + DI + e];
  float4 B0 = *(const float4*)&dbl[tf * 56 + DTR + nh * 8];
  float4 B1 = *(const float4*)&dbl[tf * 56 + DTR + nh * 8 + 4];
  float4 C0 = *(const float4*)&dbl[tf * 56 + DTR + DSN + nh * 8];
  float4 C1 = *(const float4*)&dbl[tf * 56 + DTR + DSN + nh * 8 + 4];
  // ---- carry fold (same order as before: cp ascending)
  float h[8] = {};
  for (int cp = 0; cp < c; cp++) {
#pragma unroll
    for (int j = 0; j < 8; j++)
      h[j] = carry[cp][el][nh][j] * h[j] + carry[cp][el][nh][8 + j];
  }
  // ---- pass 2: rescan with correct h0, gate, write y
  const float dpv = Dp[e];
  for (int l = l0; l < l1; l++) {
    float ndt = 0.f, nxc = 0.f, nzv = 0.f;
    float4 nB0 = {}, nB1 = {}, nC0 = {}, nC1 = {};
    if (l + 1 < l1) {
      size_t tn = tbase + l + 1;
      ndt = dt[tn * DI + e];
      nxc = xc[tn * DI + e];
      nzv = xz[tn * (2 * DI) + DI + e];
      nB0 = *(const float4*)&dbl[tn * 56 + DTR + nh * 8];
      nB1 = *(const float4*)&dbl[tn * 56 + DTR + nh * 8 + 4];
      nC0 = *(const float4*)&dbl[tn * 56 + DTR + DSN + nh * 8];
      nC1 = *(const float4*)&dbl[tn * 56 + DTR + DSN + nh * 8 + 4];
    }
    float dA[8]; dAfn(dtv, dA);
    float dx = dtv * xcv;
    float Bv[8] = {B0.x, B0.y, B0.z, B0.w, B1.x, B1.y, B1.z, B1.w};
    float Cv[8] = {C0.x, C0.y, C0.z, C0.w, C1.x, C1.y, C1.z, C1.w};
    float acc = 0.f;
#pragma unroll
    for (int j = 0; j < 8; j++) {
      h[j] = dA[j] * h[j] + dx * Bv[j];
      acc += h[j] * Cv[j];
    }
    acc += __shfl_xor(acc, 32);   // nh-pair (lanes el and el+32)
    if (nh == 0) {
      size_t t = tbase + l;
      float sz = zv * (1.f / (1.f + __expf(-zv)));
      ybf[t * DI + e] = f2bf((acc + xcv * dpv) * sz);
    }
    dtv = ndt; xcv = nxc; zv = nzv;
    B0 = nB0; B1 = nB1; C0 = nC0; C1 = nC1;
  }
}

// ---------------------------------------------------------------------------
// pure LN: u = LN(res)*nw+nb (bf16). One wave per token; no barriers.
// ---------------------------------------------------------------------------
__global__ __launch_bounds__(256) void k_ln(const float* __restrict__ res,
                                            short* __restrict__ u,
                                            const float* __restrict__ nw,
                                            const float* __restrict__ nb) {
  const int lane = threadIdx.x & 63;
  const int t = blockIdx.x * 4 + (threadIdx.x >> 6);
  float r[6];
  float s = 0.f, sq = 0.f;
#pragma unroll
  for (int j = 0; j < 6; j++) {
    int d = lane + j * 64;
    float v = res[(size_t)t * DD + d];
    r[j] = v;
    s += v; sq += v * v;
  }
#pragma unroll
  for (int o = 32; o > 0; o >>= 1) { s += __shfl_xor(s, o); sq += __shfl_xor(sq, o); }
  float mu = s * (1.f / 384.f);
  float var = sq * (1.f / 384.f) - mu * mu;
  float rs = rsqrtf(var + EPSV);
#pragma unroll
  for (int j = 0; j < 6; j++) {
    int d = lane + j * 64;
    u[(size_t)t * DD + d] = f2bf((r[j] - mu) * rs * nw[d] + nb[d]);
  }
}

// ---------------------------------------------------------------------------
// final: LN(res[b,0]) -> head. grid (8, BB). (res already includes last hid)
// ---------------------------------------------------------------------------
__global__ __launch_bounds__(256) void k_final(const float* __restrict__ res,
                                               const float* __restrict__ nfw,
                                               const float* __restrict__ nfb,
                                               const float* __restrict__ hw,
                                               const float* __restrict__ hb,
                                               float* __restrict__ out) {
  const int b = blockIdx.y;
  const int c0 = blockIdx.x * 125;
  const int tid = threadIdx.x;
  __shared__ float u0[DD];
  __shared__ float ls[4], lq[4];
  const size_t t0 = (size_t)b * LL * DD;
  float v0 = res[t0 + tid];
  float v1 = (tid < 128) ? res[t0 + 256 + tid] : 0.f;
  float s = v0 + v1, sq = v0 * v0 + v1 * v1;
#pragma unroll
  for (int o = 32; o > 0; o >>= 1) { s += __shfl_xor(s, o); sq += __shfl_xor(sq, o); }
  if ((tid & 63) == 0) { ls[tid >> 6] = s; lq[tid >> 6] = sq; }
  __syncthreads();
  float st = ls[0] + ls[1] + ls[2] + ls[3];
  float qt = lq[0] + lq[1] + lq[2] + lq[3];
  float mu = st * (1.f / 384.f);
  float var = qt * (1.f / 384.f) - mu * mu;
  float rs = rsqrtf(var + EPSV);
  u0[tid] = (v0 - mu) * rs * nfw[tid] + nfb[tid];
  if (tid < 128) u0[256 + tid] = (v1 - mu) * rs * nfw[256 + tid] + nfb[256 + tid];
  __syncthreads();
  int c = c0 + tid;
  if (tid < 125 && c < NC) {
    float acc = hb[c];
    const float* wrow = hw + (size_t)c * DD;
    for (int d = 0; d < DD; d += 4) {
      float4 w4 = *(const float4*)&wrow[d];
      acc += u0[d] * w4.x + u0[d + 1] * w4.y + u0[d + 2] * w4.z + u0[d + 3] * w4.w;
    }
    out[(size_t)b * NC + c] = acc;
  }
}

// ---------------------------------------------------------------------------
extern "C" void kernel_launch(void* const* d_in, const int* in_sizes, int n_in,
                              void* d_out, int out_size, void* d_ws, size_t ws_size,
                              hipStream_t stream) {
  const float* x       = (const float*)d_in[0];
  const float* patch_w = (const float*)d_in[1];
  const float* patch_b = (const float*)d_in[2];
  const float* cls     = (const float*)d_in[3];
  const float* pos     = (const float*)d_in[4];
  const float* in_proj = (const float*)d_in[5];
  const float* conv_w  = (const float*)d_in[6];
  const float* conv_b  = (const float*)d_in[7];
  const float* x_proj  = (const float*)d_in[8];
  const float* dt_w    = (const float*)d_in[9];
  const float* dt_b    = (const float*)d_in[10];
  const float* A_log   = (const float*)d_in[11];
  const float* D_ssm   = (const float*)d_in[12];
  const float* out_w   = (const float*)d_in[13];
  const float* norm_w  = (const float*)d_in[14];
  const float* norm_b  = (const float*)d_in[15];
  const float* normf_w = (const float*)d_in[16];
  const float* normf_b = (const float*)d_in[17];
  const float* head_w  = (const float*)d_in[18];
  const float* head_b  = (const float*)d_in[19];
  float* out = (float*)d_out;

  float* ws = (float*)d_ws;
  float* res = ws;  ws += (size_t)TT * DD;        // h accumulator (init + Σ hid)
  float* u_r = ws;  ws += (size_t)TT * DD;        // u as bf16 (half used)
  float* xzb = ws;  ws += (size_t)TT * 2 * DI;
  float* xcb = ws;  ws += (size_t)TT * DI;
  float* dbl = ws;  ws += (size_t)TT * 56;
  float* dtb = ws;  ws += (size_t)TT * DI;
  float* ybf_r = ws; ws += (size_t)TT * DI / 2;   // y bf16
  // bf16 weights (converted once per call)
  short* winbf  = (short*)ws; ws += (size_t)DEPTH * 2 * DI * DD / 2;
  short* woutbf = (short*)ws; ws += (size_t)DEPTH * DD * DI / 2;
  short* wxbf   = (short*)ws; ws += (size_t)DEPTH * 56 * DI / 2;
  short* wdtbf  = (short*)ws; ws += (size_t)DEPTH * DI * DTR / 2;

  short* u    = (short*)u_r;
  short* ybf  = (short*)ybf_r;

  // one-time weight conversions, single dispatch
  {
    int n1 = DEPTH * 2 * DI * DD;   // 14.16M
    int n2 = DEPTH * DD * DI;       // 7.08M
    int n3 = DEPTH * 56 * DI;       // 1.03M
    int n4 = DEPTH * DI * DTR;      // 0.44M
    int g1 = (n1 / 4 + 255) / 256;
    int g2 = (n2 / 4 + 255) / 256;
    int g3 = (n3 / 4 + 255) / 256;
    int g4 = (n4 / 4 + 255) / 256;
    k_cvt4<<<g1 + g2 + g3 + g4, 256, 0, stream>>>(
        in_proj, winbf, n1, out_w, woutbf, n2, x_proj, wxbf, n3, dt_w, wdtbf, n4,
        g1, g1 + g2, g1 + g2 + g3);
  }

  k_init<<<(BB * DD + 255) / 256, 256, 0, stream>>>(cls, pos, res);
  k_patch<<<dim3(49, 6), 256, 0, stream>>>(x, patch_w, patch_b, pos, res);

  for (int layer = 0; layer < DEPTH; layer++) {
    // pure LN: u = LN(res)
    k_ln<<<TT / 4, 256, 0, stream>>>(res, u, norm_w + layer * DD,
                                     norm_b + layer * DD);
    // in_proj: u_bf16 (3152,384) @ Win_bf16^T (1536,384) -> xz fp32
    k_gemm128<<<dim3(25, 12), 256, 0, stream>>>(
        u, DD, winbf + (size_t)layer * 2 * DI * DD, DD, xzb, 2 * DI, TT, 2 * DI, DD);
    // fused conv + x_proj + dt_proj (async-staged)
    k_cxd3<<<dim3(TT / 16), 256, 0, stream>>>(
        xzb, conv_w + layer * DI * 4, conv_b + layer * DI,
        wxbf + (size_t)layer * 56 * DI, wdtbf + (size_t)layer * DI * DTR,
        dt_b + layer * DI, xcb, dbl, dtb);
    // single-dispatch chunked scan (carries in LDS; exp-reduced; prefetched)
    k_scan<<<dim3(DI / 32, BB), 768, 0, stream>>>(
        dtb, xcb, xzb, dbl, A_log + (size_t)layer * DI * DSN,
        D_ssm + layer * DI, ybf);
    // out_proj with residual accumulate: res += y @ Wout^T
    k_gemm64<<<dim3(50, 6), 256, 0, stream>>>(
        ybf, DI, woutbf + (size_t)layer * DD * DI, DI, res, DD, TT, DD, DI);
  }

  k_final<<<dim3(8, BB), 256, 0, stream>>>(res, normf_w, normf_b, head_w, head_b, out);
}

// Round 10
// 2378.466 us; speedup vs baseline: 1.2052x; 1.2052x over previous
//
#include <hip/hip_runtime.h>
#include <hip/hip_bf16.h>
#include <math.h>

// Model dims
#define BB     16
#define LL     197
#define DD     384
#define DEPTH  24
#define DI     768
#define DSN    16
#define DTR    24
#define NC     1000
#define TT     (BB*LL)      // 3152 tokens
#define NPATCH 196
#define EPSV   1e-5f

// chunked scan config: 12 chunks of 17 tokens (wave = chunk in k_scan)
#define NCHUNK 12
#define CH     17
#define XZROWS 19          // conv tile: rows t0-3 .. t0+15

typedef __attribute__((ext_vector_type(8))) short short8;
typedef __attribute__((ext_vector_type(4))) short short4v;
typedef __attribute__((ext_vector_type(4))) float f32x4;

__device__ __forceinline__ short f2bf(float f) {
  union { float f; unsigned u; } v; v.f = f;
  unsigned u = v.u + 0x7fffu + ((v.u >> 16) & 1u);
  return (short)(u >> 16);
}

// async global->LDS, 16B per lane; lds dest is wave-uniform base + lane*16
__device__ __forceinline__ void gload16(const short* g, const short* l) {
  __builtin_amdgcn_global_load_lds(
      (const __attribute__((address_space(1))) unsigned int*)g,
      (__attribute__((address_space(3))) unsigned int*)l, 16, 0, 0);
}
__device__ __forceinline__ void gload16f(const float* g, const float* l) {
  __builtin_amdgcn_global_load_lds(
      (const __attribute__((address_space(1))) unsigned int*)g,
      (__attribute__((address_space(3))) unsigned int*)l, 16, 0, 0);
}

// ---------------------------------------------------------------------------
// fp32 -> bf16 bulk convert, 4 segments in one dispatch (weights, once/call)
// ---------------------------------------------------------------------------
__global__ __launch_bounds__(256) void k_cvt4(const float* __restrict__ s0, short* __restrict__ d0, int n0,
                                              const float* __restrict__ s1, short* __restrict__ d1, int n1,
                                              const float* __restrict__ s2, short* __restrict__ d2, int n2,
                                              const float* __restrict__ s3, short* __restrict__ d3, int n3,
                                              int b0, int b1, int b2) {
  int blk = blockIdx.x;
  const float* src; short* dst; int n; int lb;
  if (blk < b0)      { src = s0; dst = d0; n = n0; lb = blk; }
  else if (blk < b1) { src = s1; dst = d1; n = n1; lb = blk - b0; }
  else if (blk < b2) { src = s2; dst = d2; n = n2; lb = blk - b1; }
  else               { src = s3; dst = d3; n = n3; lb = blk - b2; }
  int i = (lb * 256 + threadIdx.x) * 4;
  if (i + 3 < n) {
    float4 v = *(const float4*)&src[i];
    short4v o = {f2bf(v.x), f2bf(v.y), f2bf(v.z), f2bf(v.w)};
    *(short4v*)&dst[i] = o;
  } else {
    for (int j = 0; i + j < n && j < 4; j++) dst[i + j] = f2bf(src[i + j]);
  }
}

// ---------------------------------------------------------------------------
// init: write cls token rows of res (res = h0; patches filled by k_patch)
// ---------------------------------------------------------------------------
__global__ __launch_bounds__(256) void k_init(const float* __restrict__ cls,
                                              const float* __restrict__ pos,
                                              float* __restrict__ res) {
  int i = blockIdx.x * 256 + threadIdx.x;
  if (i < BB * DD) {
    int b = i / DD, d = i % DD;
    res[(size_t)(b * LL) * DD + d] = cls[d] + pos[d];
  }
}

// ---------------------------------------------------------------------------
// patch embed: bf16 MFMA GEMM with fused im2col (runs once; fp32 inputs)
// writes res (= h0) directly.
// ---------------------------------------------------------------------------
__global__ __launch_bounds__(256) void k_patch(const float* __restrict__ x,
                                               const float* __restrict__ pw,
                                               const float* __restrict__ pb,
                                               const float* __restrict__ pos,
                                               float* __restrict__ res) {
  __shared__ short sA[64 * 40];
  __shared__ short sB[64 * 40];
  const int tid = threadIdx.x;
  const int m0 = blockIdx.x * 64, n0 = blockIdx.y * 64;
  const int srow = tid >> 2;
  const int skq = (tid & 3) * 8;
  const int lane = tid & 63, w = tid >> 6;
  const int wm = (w >> 1) * 32, wn = (w & 1) * 32;
  const int fr = lane & 15;
  const int fk = (lane >> 4) * 8;
  f32x4 acc[2][2] = {};
  const int m = m0 + srow;
  const int b = m / NPATCH;
  const int p = m % NPATCH;
  const int ph = p / 14, pwi = p % 14;
  const float* Wrow = pw + (size_t)(n0 + srow) * 768 + skq;
  for (int k0 = 0; k0 < 768; k0 += 32) {
    int k = k0 + skq;
    int c = k >> 8, rr = (k >> 4) & 15, kw = k & 15;
    const float* xrow = &x[(size_t)(((b * 3 + c) * 224) + (ph * 16 + rr)) * 224 +
                           (pwi * 16 + kw)];
    float4 a0 = *(const float4*)&xrow[0];
    float4 a1 = *(const float4*)&xrow[4];
    float4 b0 = *(const float4*)&Wrow[k0];
    float4 b1 = *(const float4*)&Wrow[k0 + 4];
    short8 av = {f2bf(a0.x), f2bf(a0.y), f2bf(a0.z), f2bf(a0.w),
                 f2bf(a1.x), f2bf(a1.y), f2bf(a1.z), f2bf(a1.w)};
    short8 bv = {f2bf(b0.x), f2bf(b0.y), f2bf(b0.z), f2bf(b0.w),
                 f2bf(b1.x), f2bf(b1.y), f2bf(b1.z), f2bf(b1.w)};
    *(short8*)&sA[srow * 40 + skq] = av;
    *(short8*)&sB[srow * 40 + skq] = bv;
    __syncthreads();
    short8 af0 = *(const short8*)&sA[(wm + fr) * 40 + fk];
    short8 af1 = *(const short8*)&sA[(wm + 16 + fr) * 40 + fk];
    short8 bf0 = *(const short8*)&sB[(wn + fr) * 40 + fk];
    short8 bf1 = *(const short8*)&sB[(wn + 16 + fr) * 40 + fk];
    acc[0][0] = __builtin_amdgcn_mfma_f32_16x16x32_bf16(af0, bf0, acc[0][0], 0, 0, 0);
    acc[0][1] = __builtin_amdgcn_mfma_f32_16x16x32_bf16(af0, bf1, acc[0][1], 0, 0, 0);
    acc[1][0] = __builtin_amdgcn_mfma_f32_16x16x32_bf16(af1, bf0, acc[1][0], 0, 0, 0);
    acc[1][1] = __builtin_amdgcn_mfma_f32_16x16x32_bf16(af1, bf1, acc[1][1], 0, 0, 0);
    __syncthreads();
  }
#pragma unroll
  for (int i = 0; i < 2; i++)
#pragma unroll
    for (int j = 0; j < 2; j++)
#pragma unroll
      for (int q = 0; q < 4; q++) {
        int mm = m0 + wm + i * 16 + (lane >> 4) * 4 + q;
        int nn = n0 + wn + j * 16 + (lane & 15);
        int b2 = mm / NPATCH, pp = mm % NPATCH;
        int tok = b2 * LL + 1 + pp;
        res[(size_t)tok * DD + nn] = acc[i][j][q] + pb[nn] + pos[(size_t)(1 + pp) * DD + nn];
      }
}

// ---------------------------------------------------------------------------
// m97-style 128x128 bf16 GEMM: C[M,N] = A[M,K] * W[N,K]^T. (in_proj)
// ---------------------------------------------------------------------------
__global__ __launch_bounds__(256) void k_gemm128(const short* __restrict__ A, int lda,
                                                 const short* __restrict__ W, int ldb,
                                                 float* __restrict__ C, int ldc,
                                                 int M, int N, int K) {
  __shared__ short sA[128 * 32];
  __shared__ short sB[128 * 32];
  const int tid = threadIdx.x;
  const int lane = tid & 63, w = tid >> 6;
  const int m0 = blockIdx.x * 128, n0 = blockIdx.y * 128;
  const int wm = (w >> 1) * 64, wn = (w & 1) * 64;
  const int fr = lane & 15;
  const int fk = (lane >> 4) * 8;
  const int q0 = w * 2, q1 = w * 2 + 1;
  const int sr0 = q0 * 16 + (lane >> 2);
  const int sr1 = q1 * 16 + (lane >> 2);
  const int scol = (lane & 3) * 8;
  f32x4 acc[4][4] = {};
  const short* Ab0 = A + (size_t)(m0 + sr0) * lda + scol;
  const short* Ab1 = A + (size_t)(m0 + sr1) * lda + scol;
  const short* Bb0 = W + (size_t)(n0 + sr0) * ldb + scol;
  const short* Bb1 = W + (size_t)(n0 + sr1) * ldb + scol;
  for (int k0 = 0; k0 < K; k0 += 32) {
    gload16(Ab0 + k0, &sA[q0 * 512]);
    gload16(Ab1 + k0, &sA[q1 * 512]);
    gload16(Bb0 + k0, &sB[q0 * 512]);
    gload16(Bb1 + k0, &sB[q1 * 512]);
    __syncthreads();
    short8 af[4], bf[4];
#pragma unroll
    for (int i = 0; i < 4; i++) {
      af[i] = *(const short8*)&sA[(wm + i * 16 + fr) * 32 + fk];
      bf[i] = *(const short8*)&sB[(wn + i * 16 + fr) * 32 + fk];
    }
#pragma unroll
    for (int i = 0; i < 4; i++)
#pragma unroll
      for (int j = 0; j < 4; j++)
        acc[i][j] = __builtin_amdgcn_mfma_f32_16x16x32_bf16(af[i], bf[j], acc[i][j], 0, 0, 0);
    __syncthreads();
  }
#pragma unroll
  for (int i = 0; i < 4; i++)
#pragma unroll
    for (int j = 0; j < 4; j++)
#pragma unroll
      for (int q = 0; q < 4; q++) {
        int mm = m0 + wm + i * 16 + (lane >> 4) * 4 + q;
        int nn = n0 + wn + j * 16 + fr;
        if (mm < M) C[(size_t)mm * ldc + nn] = acc[i][j][q];
      }
}

// ---------------------------------------------------------------------------
// 64x64 bf16 GEMM, out_proj with residual accumulate: res += y @ Wout^T
// ---------------------------------------------------------------------------
__global__ __launch_bounds__(256) void k_gemm64(const short* __restrict__ A, int lda,
                                                const short* __restrict__ W, int ldb,
                                                float* __restrict__ C, int ldc,
                                                int M, int N, int K) {
  __shared__ short sA[64 * 32];
  __shared__ short sB[64 * 32];
  const int tid = threadIdx.x;
  const int lane = tid & 63, w = tid >> 6;
  const int m0 = blockIdx.x * 64, n0 = blockIdx.y * 64;
  const int wm = (w >> 1) * 32, wn = (w & 1) * 32;
  const int fr = lane & 15;
  const int fk = (lane >> 4) * 8;
  const int srow = w * 16 + (lane >> 2);
  const int scol = (lane & 3) * 8;
  f32x4 acc[2][2] = {};
  const short* Ab = A + (size_t)(m0 + srow) * lda + scol;
  const short* Bb = W + (size_t)(n0 + srow) * ldb + scol;
  for (int k0 = 0; k0 < K; k0 += 32) {
    gload16(Ab + k0, &sA[w * 512]);
    gload16(Bb + k0, &sB[w * 512]);
    __syncthreads();
    short8 af0 = *(const short8*)&sA[(wm + fr) * 32 + fk];
    short8 af1 = *(const short8*)&sA[(wm + 16 + fr) * 32 + fk];
    short8 bf0 = *(const short8*)&sB[(wn + fr) * 32 + fk];
    short8 bf1 = *(const short8*)&sB[(wn + 16 + fr) * 32 + fk];
    acc[0][0] = __builtin_amdgcn_mfma_f32_16x16x32_bf16(af0, bf0, acc[0][0], 0, 0, 0);
    acc[0][1] = __builtin_amdgcn_mfma_f32_16x16x32_bf16(af0, bf1, acc[0][1], 0, 0, 0);
    acc[1][0] = __builtin_amdgcn_mfma_f32_16x16x32_bf16(af1, bf0, acc[1][0], 0, 0, 0);
    acc[1][1] = __builtin_amdgcn_mfma_f32_16x16x32_bf16(af1, bf1, acc[1][1], 0, 0, 0);
    __syncthreads();
  }
#pragma unroll
  for (int i = 0; i < 2; i++)
#pragma unroll
    for (int j = 0; j < 2; j++)
#pragma unroll
      for (int q = 0; q < 4; q++) {
        int mm = m0 + wm + i * 16 + (lane >> 4) * 4 + q;
        int nn = n0 + wn + j * 16 + fr;
        if (mm < M) C[(size_t)mm * ldc + nn] += acc[i][j][q];
      }
}

// ---------------------------------------------------------------------------
// FUSED conv + x_proj + dt_proj with ASYNC LDS staging (unchanged from R8).
// ---------------------------------------------------------------------------
__global__ __launch_bounds__(256, 1) void k_cxd3(const float* __restrict__ xz,
                                                 const float* __restrict__ wc,
                                                 const float* __restrict__ bc,
                                                 const short* __restrict__ wx,
                                                 const short* __restrict__ wdt,
                                                 const float* __restrict__ dbias,
                                                 float* __restrict__ xc,
                                                 float* __restrict__ dbl,
                                                 float* __restrict__ dtb) {
  __shared__ float sXZ[XZROWS * 768];   // 58368 B
  __shared__ float sWC[768 * 4];        // 12288 B
  __shared__ float sBC[768];            //  3072 B
  __shared__ short sXC[16 * 776];       // 24832 B
  __shared__ short sDT[16 * 40];        //  1280 B
  const int tid = threadIdx.x;
  const int t0 = blockIdx.x * 16;
  const int lane = tid & 63, wv = tid >> 6;
  // ---- phase 0: async staging (DMA; one drain at the barrier)
  for (int r = wv; r < XZROWS; r += 4) {
    int srow = t0 - 3 + r; if (srow < 0) srow = 0;
    const float* src = xz + (size_t)srow * (2 * DI);
#pragma unroll
    for (int s = 0; s < 3; s++)
      gload16f(src + s * 256 + lane * 4, &sXZ[r * 768 + s * 256]);
  }
#pragma unroll
  for (int s = 0; s < 3; s++) {
    int off = (wv * 3 + s) * 256;
    gload16f(wc + off + lane * 4, &sWC[off]);
  }
  if (wv < 3) {
    int off = wv * 256;
    gload16f(bc + off + lane * 4, &sBC[off]);
  }
  __syncthreads();   // compiler drains vmcnt before barrier
  // ---- phase 1: conv + SiLU from LDS (16 tokens x 192 groups; 12/thread)
#pragma unroll
  for (int it = 0; it < 12; it++) {
    int g = tid + it * 256;
    int tl = g / 192, eg = g % 192;
    int e = eg * 4;
    int t = t0 + tl;
    int l = t % LL;
    const float* baseL = &sXZ[(tl + 3) * 768 + e];
    float4 w0 = *(const float4*)&sWC[(e + 0) * 4];
    float4 w1 = *(const float4*)&sWC[(e + 1) * 4];
    float4 w2 = *(const float4*)&sWC[(e + 2) * 4];
    float4 w3 = *(const float4*)&sWC[(e + 3) * 4];
    float4 acc = *(const float4*)&sBC[e];
    if (l >= 3) {
      float4 xv = *(const float4*)&baseL[-3 * 768];
      acc.x += xv.x * w0.x; acc.y += xv.y * w1.x; acc.z += xv.z * w2.x; acc.w += xv.w * w3.x;
    }
    if (l >= 2) {
      float4 xv = *(const float4*)&baseL[-2 * 768];
      acc.x += xv.x * w0.y; acc.y += xv.y * w1.y; acc.z += xv.z * w2.y; acc.w += xv.w * w3.y;
    }
    if (l >= 1) {
      float4 xv = *(const float4*)&baseL[-768];
      acc.x += xv.x * w0.z; acc.y += xv.y * w1.z; acc.z += xv.z * w2.z; acc.w += xv.w * w3.z;
    }
    {
      float4 xv = *(const float4*)&baseL[0];
      acc.x += xv.x * w0.w; acc.y += xv.y * w1.w; acc.z += xv.z * w2.w; acc.w += xv.w * w3.w;
    }
    acc.x = acc.x / (1.f + __expf(-acc.x));
    acc.y = acc.y / (1.f + __expf(-acc.y));
    acc.z = acc.z / (1.f + __expf(-acc.z));
    acc.w = acc.w / (1.f + __expf(-acc.w));
    *(float4*)&xc[(size_t)t * DI + e] = acc;
    short4v ov = {f2bf(acc.x), f2bf(acc.y), f2bf(acc.z), f2bf(acc.w)};
    *(short4v*)&sXC[tl * 776 + e] = ov;
  }
  __syncthreads();
  // ---- phase 2: x_proj (A from sXC, W from L2-hot global, no barriers)
  const int fr = lane & 15;
  const int fk = (lane >> 4) * 8;
  f32x4 acc0 = {}, acc1 = {};
  const short* Wrow = wx + (size_t)(wv * 16 + fr) * DI + fk;
#pragma unroll
  for (int k0 = 0; k0 < DI; k0 += 64) {
    short8 af0 = *(const short8*)&sXC[fr * 776 + k0 + fk];
    short8 bf0 = *(const short8*)&Wrow[k0];
    short8 af1 = *(const short8*)&sXC[fr * 776 + k0 + 32 + fk];
    short8 bf1 = *(const short8*)&Wrow[k0 + 32];
    acc0 = __builtin_amdgcn_mfma_f32_16x16x32_bf16(af0, bf0, acc0, 0, 0, 0);
    acc1 = __builtin_amdgcn_mfma_f32_16x16x32_bf16(af1, bf1, acc1, 0, 0, 0);
  }
  f32x4 accx = acc0 + acc1;
  // ---- phase 3: scatter dbl (cols 24..55) + sDT (cols 0..23, pad 0)
  {
    int nn = wv * 16 + fr;
#pragma unroll
    for (int q = 0; q < 4; q++) {
      int row = (lane >> 4) * 4 + q;
      int t = t0 + row;
      if (nn >= DTR && nn < 56) dbl[(size_t)t * 56 + nn] = accx[q];
      if (wv < 2) sDT[row * 40 + nn] = (nn < DTR) ? f2bf(accx[q]) : (short)0;
    }
  }
  __syncthreads();
  // ---- phase 4: dt_proj (M=16, N=768, K=24 pad 32), W from global
  short8 adt = *(const short8*)&sDT[fr * 40 + fk];
  const int g = lane >> 4;
#pragma unroll
  for (int jj = 0; jj < 12; jj++) {
    int j = wv * 12 + jj;
    short8 bdt = short8{0, 0, 0, 0, 0, 0, 0, 0};
    if (g < 3) bdt = *(const short8*)&wdt[(size_t)(j * 16 + fr) * DTR + g * 8];
    f32x4 p = {};
    p = __builtin_amdgcn_mfma_f32_16x16x32_bf16(adt, bdt, p, 0, 0, 0);
    int nc = j * 16 + fr;
    float bv = dbias[nc];
#pragma unroll
    for (int q = 0; q < 4; q++) {
      int t = t0 + (lane >> 4) * 4 + q;
      float v = p[q] + bv;
      v = (v > 20.f) ? v : __logf(1.f + __expf(v));
      dtb[(size_t)t * DI + nc] = v;
    }
  }
}

// ---------------------------------------------------------------------------
// SINGLE-DISPATCH chunked scan — R8 loop structure (no prefetch), with ONLY
// the exp-reduction applied: dA[j] = exp(dt*negA[j]) computed as powers of
// p = exp(-dt) when A_log has the arange structure (wave-uniform check;
// generic 8-expf fallback preserved for correctness on any input).
// ---------------------------------------------------------------------------
__global__ __launch_bounds__(768) void k_scan(const float* __restrict__ dt,
                                              const float* __restrict__ xc,
                                              const float* __restrict__ xz,
                                              const float* __restrict__ dbl,
                                              const float* __restrict__ Alog,
                                              const float* __restrict__ Dp,
                                              short* __restrict__ ybf) {
  __shared__ float carry[NCHUNK][32][2][17];  // [c][e][nh][0..7 Aprod, 8..15 Hend]
  const int tid = threadIdx.x;
  const int c  = tid >> 6;          // wave index = chunk
  const int nh = (tid >> 5) & 1;
  const int el = tid & 31;
  const int e  = blockIdx.x * 32 + el;
  const int b  = blockIdx.y;
  float4 al0 = *(const float4*)&Alog[(size_t)e * DSN + nh * 8];
  float4 al1 = *(const float4*)&Alog[(size_t)e * DSN + nh * 8 + 4];
  float negA[8] = {-__expf(al0.x), -__expf(al0.y), -__expf(al0.z), -__expf(al0.w),
                   -__expf(al1.x), -__expf(al1.y), -__expf(al1.z), -__expf(al1.w)};
  // A_log arange-structure check: negA[j] ?= -(nh*8+j+1). Wave-uniform.
  bool fa = true;
#pragma unroll
  for (int j = 0; j < 8; j++) {
    float expect = (float)(nh * 8 + j + 1);
    fa = fa && (fabsf(negA[j] + expect) <= 1e-3f * expect);
  }
  const bool fastA = __all(fa);
  const int l0 = c * CH;
  const int l1 = (l0 + CH < LL) ? (l0 + CH) : LL;
  const size_t tbase = (size_t)b * LL;
  // ---- pass 1: local chunk scan (last chunk's carry never consumed)
  if (c < NCHUNK - 1) {
    float h[8] = {};
    float asum = 0.f;
    for (int l = l0; l < l1; l++) {
      size_t t = tbase + l;
      float dtv = dt[t * DI + e];
      float xcv = xc[t * DI + e];
      float4 B0 = *(const float4*)&dbl[t * 56 + DTR + nh * 8];
      float4 B1 = *(const float4*)&dbl[t * 56 + DTR + nh * 8 + 4];
      float dA[8];
      if (fastA) {
        float p = __expf(-dtv);
        float p2 = p * p, p4 = p2 * p2;
        float cur = nh ? (p4 * p4) : 1.f;
#pragma unroll
        for (int j = 0; j < 8; j++) { cur *= p; dA[j] = cur; }
      } else {
#pragma unroll
        for (int j = 0; j < 8; j++) dA[j] = __expf(dtv * negA[j]);
      }
      float dx = dtv * xcv;
      float Bv[8] = {B0.x, B0.y, B0.z, B0.w, B1.x, B1.y, B1.z, B1.w};
#pragma unroll
      for (int j = 0; j < 8; j++)
        h[j] = dA[j] * h[j] + dx * Bv[j];
      asum += dtv;
    }
    float cA[8];
    if (fastA) {
      float p = __expf(-asum);
      float p2 = p * p, p4 = p2 * p2;
      float cur = nh ? (p4 * p4) : 1.f;
#pragma unroll
      for (int j = 0; j < 8; j++) { cur *= p; cA[j] = cur; }
    } else {
#pragma unroll
      for (int j = 0; j < 8; j++) cA[j] = __expf(asum * negA[j]);
    }
#pragma unroll
    for (int j = 0; j < 8; j++) {
      carry[c][el][nh][j]     = cA[j];
      carry[c][el][nh][8 + j] = h[j];
    }
  }
  __syncthreads();
  // ---- carry fold (same order as before: cp ascending)
  float h[8] = {};
  for (int cp = 0; cp < c; cp++) {
#pragma unroll
    for (int j = 0; j < 8; j++)
      h[j] = carry[cp][el][nh][j] * h[j] + carry[cp][el][nh][8 + j];
  }
  // ---- pass 2: rescan with correct h0, gate, write y
  const float dpv = Dp[e];
  for (int l = l0; l < l1; l++) {
    size_t t = tbase + l;
    float dtv = dt[t * DI + e];
    float xcv = xc[t * DI + e];
    float zv = xz[t * (2 * DI) + DI + e];
    float4 B0 = *(const float4*)&dbl[t * 56 + DTR + nh * 8];
    float4 B1 = *(const float4*)&dbl[t * 56 + DTR + nh * 8 + 4];
    float4 C0 = *(const float4*)&dbl[t * 56 + DTR + DSN + nh * 8];
    float4 C1 = *(const float4*)&dbl[t * 56 + DTR + DSN + nh * 8 + 4];
    float dA[8];
    if (fastA) {
      float p = __expf(-dtv);
      float p2 = p * p, p4 = p2 * p2;
      float cur = nh ? (p4 * p4) : 1.f;
#pragma unroll
      for (int j = 0; j < 8; j++) { cur *= p; dA[j] = cur; }
    } else {
#pragma unroll
      for (int j = 0; j < 8; j++) dA[j] = __expf(dtv * negA[j]);
    }
    float dx = dtv * xcv;
    float Bv[8] = {B0.x, B0.y, B0.z, B0.w, B1.x, B1.y, B1.z, B1.w};
    float Cv[8] = {C0.x, C0.y, C0.z, C0.w, C1.x, C1.y, C1.z, C1.w};
    float acc = 0.f;
#pragma unroll
    for (int j = 0; j < 8; j++) {
      h[j] = dA[j] * h[j] + dx * Bv[j];
      acc += h[j] * Cv[j];
    }
    acc += __shfl_xor(acc, 32);   // nh-pair (lanes el and el+32)
    if (nh == 0) {
      float sz = zv * (1.f / (1.f + __expf(-zv)));
      ybf[t * DI + e] = f2bf((acc + xcv * dpv) * sz);
    }
  }
}

// ---------------------------------------------------------------------------
// pure LN: u = LN(res)*nw+nb (bf16). One wave per token; no barriers.
// ---------------------------------------------------------------------------
__global__ __launch_bounds__(256) void k_ln(const float* __restrict__ res,
                                            short* __restrict__ u,
                                            const float* __restrict__ nw,
                                            const float* __restrict__ nb) {
  const int lane = threadIdx.x & 63;
  const int t = blockIdx.x * 4 + (threadIdx.x >> 6);
  float r[6];
  float s = 0.f, sq = 0.f;
#pragma unroll
  for (int j = 0; j < 6; j++) {
    int d = lane + j * 64;
    float v = res[(size_t)t * DD + d];
    r[j] = v;
    s += v; sq += v * v;
  }
#pragma unroll
  for (int o = 32; o > 0; o >>= 1) { s += __shfl_xor(s, o); sq += __shfl_xor(sq, o); }
  float mu = s * (1.f / 384.f);
  float var = sq * (1.f / 384.f) - mu * mu;
  float rs = rsqrtf(var + EPSV);
#pragma unroll
  for (int j = 0; j < 6; j++) {
    int d = lane + j * 64;
    u[(size_t)t * DD + d] = f2bf((r[j] - mu) * rs * nw[d] + nb[d]);
  }
}

// ---------------------------------------------------------------------------
// final: LN(res[b,0]) -> head. grid (8, BB). (res already includes last hid)
// ---------------------------------------------------------------------------
__global__ __launch_bounds__(256) void k_final(const float* __restrict__ res,
                                               const float* __restrict__ nfw,
                                               const float* __restrict__ nfb,
                                               const float* __restrict__ hw,
                                               const float* __restrict__ hb,
                                               float* __restrict__ out) {
  const int b = blockIdx.y;
  const int c0 = blockIdx.x * 125;
  const int tid = threadIdx.x;
  __shared__ float u0[DD];
  __shared__ float ls[4], lq[4];
  const size_t t0 = (size_t)b * LL * DD;
  float v0 = res[t0 + tid];
  float v1 = (tid < 128) ? res[t0 + 256 + tid] : 0.f;
  float s = v0 + v1, sq = v0 * v0 + v1 * v1;
#pragma unroll
  for (int o = 32; o > 0; o >>= 1) { s += __shfl_xor(s, o); sq += __shfl_xor(sq, o); }
  if ((tid & 63) == 0) { ls[tid >> 6] = s; lq[tid >> 6] = sq; }
  __syncthreads();
  float st = ls[0] + ls[1] + ls[2] + ls[3];
  float qt = lq[0] + lq[1] + lq[2] + lq[3];
  float mu = st * (1.f / 384.f);
  float var = qt * (1.f / 384.f) - mu * mu;
  float rs = rsqrtf(var + EPSV);
  u0[tid] = (v0 - mu) * rs * nfw[tid] + nfb[tid];
  if (tid < 128) u0[256 + tid] = (v1 - mu) * rs * nfw[256 + tid] + nfb[256 + tid];
  __syncthreads();
  int c = c0 + tid;
  if (tid < 125 && c < NC) {
    float acc = hb[c];
    const float* wrow = hw + (size_t)c * DD;
    for (int d = 0; d < DD; d += 4) {
      float4 w4 = *(const float4*)&wrow[d];
      acc += u0[d] * w4.x + u0[d + 1] * w4.y + u0[d + 2] * w4.z + u0[d + 3] * w4.w;
    }
    out[(size_t)b * NC + c] = acc;
  }
}

// ---------------------------------------------------------------------------
extern "C" void kernel_launch(void* const* d_in, const int* in_sizes, int n_in,
                              void* d_out, int out_size, void* d_ws, size_t ws_size,
                              hipStream_t stream) {
  const float* x       = (const float*)d_in[0];
  const float* patch_w = (const float*)d_in[1];
  const float* patch_b = (const float*)d_in[2];
  const float* cls     = (const float*)d_in[3];
  const float* pos     = (const float*)d_in[4];
  const float* in_proj = (const float*)d_in[5];
  const float* conv_w  = (const float*)d_in[6];
  const float* conv_b  = (const float*)d_in[7];
  const float* x_proj  = (const float*)d_in[8];
  const float* dt_w    = (const float*)d_in[9];
  const float* dt_b    = (const float*)d_in[10];
  const float* A_log   = (const float*)d_in[11];
  const float* D_ssm   = (const float*)d_in[12];
  const float* out_w   = (const float*)d_in[13];
  const float* norm_w  = (const float*)d_in[14];
  const float* norm_b  = (const float*)d_in[15];
  const float* normf_w = (const float*)d_in[16];
  const float* normf_b = (const float*)d_in[17];
  const float* head_w  = (const float*)d_in[18];
  const float* head_b  = (const float*)d_in[19];
  float* out = (float*)d_out;

  float* ws = (float*)d_ws;
  float* res = ws;  ws += (size_t)TT * DD;        // h accumulator (init + Σ hid)
  float* u_r = ws;  ws += (size_t)TT * DD;        // u as bf16 (half used)
  float* xzb = ws;  ws += (size_t)TT * 2 * DI;
  float* xcb = ws;  ws += (size_t)TT * DI;
  float* dbl = ws;  ws += (size_t)TT * 56;
  float* dtb = ws;  ws += (size_t)TT * DI;
  float* ybf_r = ws; ws += (size_t)TT * DI / 2;   // y bf16
  // bf16 weights (converted once per call)
  short* winbf  = (short*)ws; ws += (size_t)DEPTH * 2 * DI * DD / 2;
  short* woutbf = (short*)ws; ws += (size_t)DEPTH * DD * DI / 2;
  short* wxbf   = (short*)ws; ws += (size_t)DEPTH * 56 * DI / 2;
  short* wdtbf  = (short*)ws; ws += (size_t)DEPTH * DI * DTR / 2;

  short* u    = (short*)u_r;
  short* ybf  = (short*)ybf_r;

  // one-time weight conversions, single dispatch
  {
    int n1 = DEPTH * 2 * DI * DD;   // 14.16M
    int n2 = DEPTH * DD * DI;       // 7.08M
    int n3 = DEPTH * 56 * DI;       // 1.03M
    int n4 = DEPTH * DI * DTR;      // 0.44M
    int g1 = (n1 / 4 + 255) / 256;
    int g2 = (n2 / 4 + 255) / 256;
    int g3 = (n3 / 4 + 255) / 256;
    int g4 = (n4 / 4 + 255) / 256;
    k_cvt4<<<g1 + g2 + g3 + g4, 256, 0, stream>>>(
        in_proj, winbf, n1, out_w, woutbf, n2, x_proj, wxbf, n3, dt_w, wdtbf, n4,
        g1, g1 + g2, g1 + g2 + g3);
  }

  k_init<<<(BB * DD + 255) / 256, 256, 0, stream>>>(cls, pos, res);
  k_patch<<<dim3(49, 6), 256, 0, stream>>>(x, patch_w, patch_b, pos, res);

  for (int layer = 0; layer < DEPTH; layer++) {
    // pure LN: u = LN(res)
    k_ln<<<TT / 4, 256, 0, stream>>>(res, u, norm_w + layer * DD,
                                     norm_b + layer * DD);
    // in_proj: u_bf16 (3152,384) @ Win_bf16^T (1536,384) -> xz fp32
    k_gemm128<<<dim3(25, 12), 256, 0, stream>>>(
        u, DD, winbf + (size_t)layer * 2 * DI * DD, DD, xzb, 2 * DI, TT, 2 * DI, DD);
    // fused conv + x_proj + dt_proj (async-staged)
    k_cxd3<<<dim3(TT / 16), 256, 0, stream>>>(
        xzb, conv_w + layer * DI * 4, conv_b + layer * DI,
        wxbf + (size_t)layer * 56 * DI, wdtbf + (size_t)layer * DI * DTR,
        dt_b + layer * DI, xcb, dbl, dtb);
    // single-dispatch chunked scan (carries in LDS; exp-reduced only)
    k_scan<<<dim3(DI / 32, BB), 768, 0, stream>>>(
        dtb, xcb, xzb, dbl, A_log + (size_t)layer * DI * DSN,
        D_ssm + layer * DI, ybf);
    // out_proj with residual accumulate: res += y @ Wout^T
    k_gemm64<<<dim3(50, 6), 256, 0, stream>>>(
        ybf, DI, woutbf + (size_t)layer * DD * DI, DI, res, DD, TT, DD, DI);
  }

  k_final<<<dim3(8, BB), 256, 0, stream>>>(res, normf_w, normf_b, head_w, head_b, out);
}

// Round 11
// 2351.367 us; speedup vs baseline: 1.2191x; 1.0115x over previous
//
#include <hip/hip_runtime.h>
#include <hip/hip_bf16.h>
#include <math.h>

// Model dims
#define BB     16
#define LL     197
#define DD     384
#define DEPTH  24
#define DI     768
#define DSN    16
#define DTR    24
#define NC     1000
#define TT     (BB*LL)      // 3152 tokens
#define NPATCH 196
#define EPSV   1e-5f

// chunked scan config: 16 chunks of 13 tokens (wave = chunk in k_scan)
#define NCHUNK 16
#define CH     13
#define XZROWS 19          // conv tile: rows t0-3 .. t0+15

typedef __attribute__((ext_vector_type(8))) short short8;
typedef __attribute__((ext_vector_type(4))) short short4v;
typedef __attribute__((ext_vector_type(4))) float f32x4;

__device__ __forceinline__ short f2bf(float f) {
  union { float f; unsigned u; } v; v.f = f;
  unsigned u = v.u + 0x7fffu + ((v.u >> 16) & 1u);
  return (short)(u >> 16);
}

// async global->LDS, 16B per lane; lds dest is wave-uniform base + lane*16
__device__ __forceinline__ void gload16(const short* g, const short* l) {
  __builtin_amdgcn_global_load_lds(
      (const __attribute__((address_space(1))) unsigned int*)g,
      (__attribute__((address_space(3))) unsigned int*)l, 16, 0, 0);
}
__device__ __forceinline__ void gload16f(const float* g, const float* l) {
  __builtin_amdgcn_global_load_lds(
      (const __attribute__((address_space(1))) unsigned int*)g,
      (__attribute__((address_space(3))) unsigned int*)l, 16, 0, 0);
}

// ---------------------------------------------------------------------------
// fp32 -> bf16 bulk convert, 4 segments in one dispatch (weights, once/call)
// ---------------------------------------------------------------------------
__global__ __launch_bounds__(256) void k_cvt4(const float* __restrict__ s0, short* __restrict__ d0, int n0,
                                              const float* __restrict__ s1, short* __restrict__ d1, int n1,
                                              const float* __restrict__ s2, short* __restrict__ d2, int n2,
                                              const float* __restrict__ s3, short* __restrict__ d3, int n3,
                                              int b0, int b1, int b2) {
  int blk = blockIdx.x;
  const float* src; short* dst; int n; int lb;
  if (blk < b0)      { src = s0; dst = d0; n = n0; lb = blk; }
  else if (blk < b1) { src = s1; dst = d1; n = n1; lb = blk - b0; }
  else if (blk < b2) { src = s2; dst = d2; n = n2; lb = blk - b1; }
  else               { src = s3; dst = d3; n = n3; lb = blk - b2; }
  int i = (lb * 256 + threadIdx.x) * 4;
  if (i + 3 < n) {
    float4 v = *(const float4*)&src[i];
    short4v o = {f2bf(v.x), f2bf(v.y), f2bf(v.z), f2bf(v.w)};
    *(short4v*)&dst[i] = o;
  } else {
    for (int j = 0; i + j < n && j < 4; j++) dst[i + j] = f2bf(src[i + j]);
  }
}

// ---------------------------------------------------------------------------
// init: write cls token rows of res (res = h0; patches filled by k_patch)
// ---------------------------------------------------------------------------
__global__ __launch_bounds__(256) void k_init(const float* __restrict__ cls,
                                              const float* __restrict__ pos,
                                              float* __restrict__ res) {
  int i = blockIdx.x * 256 + threadIdx.x;
  if (i < BB * DD) {
    int b = i / DD, d = i % DD;
    res[(size_t)(b * LL) * DD + d] = cls[d] + pos[d];
  }
}

// ---------------------------------------------------------------------------
// patch embed: bf16 MFMA GEMM with fused im2col (runs once; fp32 inputs)
// writes res (= h0) directly.
// ---------------------------------------------------------------------------
__global__ __launch_bounds__(256) void k_patch(const float* __restrict__ x,
                                               const float* __restrict__ pw,
                                               const float* __restrict__ pb,
                                               const float* __restrict__ pos,
                                               float* __restrict__ res) {
  __shared__ short sA[64 * 40];
  __shared__ short sB[64 * 40];
  const int tid = threadIdx.x;
  const int m0 = blockIdx.x * 64, n0 = blockIdx.y * 64;
  const int srow = tid >> 2;
  const int skq = (tid & 3) * 8;
  const int lane = tid & 63, w = tid >> 6;
  const int wm = (w >> 1) * 32, wn = (w & 1) * 32;
  const int fr = lane & 15;
  const int fk = (lane >> 4) * 8;
  f32x4 acc[2][2] = {};
  const int m = m0 + srow;
  const int b = m / NPATCH;
  const int p = m % NPATCH;
  const int ph = p / 14, pwi = p % 14;
  const float* Wrow = pw + (size_t)(n0 + srow) * 768 + skq;
  for (int k0 = 0; k0 < 768; k0 += 32) {
    int k = k0 + skq;
    int c = k >> 8, rr = (k >> 4) & 15, kw = k & 15;
    const float* xrow = &x[(size_t)(((b * 3 + c) * 224) + (ph * 16 + rr)) * 224 +
                           (pwi * 16 + kw)];
    float4 a0 = *(const float4*)&xrow[0];
    float4 a1 = *(const float4*)&xrow[4];
    float4 b0 = *(const float4*)&Wrow[k0];
    float4 b1 = *(const float4*)&Wrow[k0 + 4];
    short8 av = {f2bf(a0.x), f2bf(a0.y), f2bf(a0.z), f2bf(a0.w),
                 f2bf(a1.x), f2bf(a1.y), f2bf(a1.z), f2bf(a1.w)};
    short8 bv = {f2bf(b0.x), f2bf(b0.y), f2bf(b0.z), f2bf(b0.w),
                 f2bf(b1.x), f2bf(b1.y), f2bf(b1.z), f2bf(b1.w)};
    *(short8*)&sA[srow * 40 + skq] = av;
    *(short8*)&sB[srow * 40 + skq] = bv;
    __syncthreads();
    short8 af0 = *(const short8*)&sA[(wm + fr) * 40 + fk];
    short8 af1 = *(const short8*)&sA[(wm + 16 + fr) * 40 + fk];
    short8 bf0 = *(const short8*)&sB[(wn + fr) * 40 + fk];
    short8 bf1 = *(const short8*)&sB[(wn + 16 + fr) * 40 + fk];
    acc[0][0] = __builtin_amdgcn_mfma_f32_16x16x32_bf16(af0, bf0, acc[0][0], 0, 0, 0);
    acc[0][1] = __builtin_amdgcn_mfma_f32_16x16x32_bf16(af0, bf1, acc[0][1], 0, 0, 0);
    acc[1][0] = __builtin_amdgcn_mfma_f32_16x16x32_bf16(af1, bf0, acc[1][0], 0, 0, 0);
    acc[1][1] = __builtin_amdgcn_mfma_f32_16x16x32_bf16(af1, bf1, acc[1][1], 0, 0, 0);
    __syncthreads();
  }
#pragma unroll
  for (int i = 0; i < 2; i++)
#pragma unroll
    for (int j = 0; j < 2; j++)
#pragma unroll
      for (int q = 0; q < 4; q++) {
        int mm = m0 + wm + i * 16 + (lane >> 4) * 4 + q;
        int nn = n0 + wn + j * 16 + (lane & 15);
        int b2 = mm / NPATCH, pp = mm % NPATCH;
        int tok = b2 * LL + 1 + pp;
        res[(size_t)tok * DD + nn] = acc[i][j][q] + pb[nn] + pos[(size_t)(1 + pp) * DD + nn];
      }
}

// ---------------------------------------------------------------------------
// m97-style 128x128 bf16 GEMM: C[M,N] = A[M,K] * W[N,K]^T. (in_proj)
// ---------------------------------------------------------------------------
__global__ __launch_bounds__(256) void k_gemm128(const short* __restrict__ A, int lda,
                                                 const short* __restrict__ W, int ldb,
                                                 float* __restrict__ C, int ldc,
                                                 int M, int N, int K) {
  __shared__ short sA[128 * 32];
  __shared__ short sB[128 * 32];
  const int tid = threadIdx.x;
  const int lane = tid & 63, w = tid >> 6;
  const int m0 = blockIdx.x * 128, n0 = blockIdx.y * 128;
  const int wm = (w >> 1) * 64, wn = (w & 1) * 64;
  const int fr = lane & 15;
  const int fk = (lane >> 4) * 8;
  const int q0 = w * 2, q1 = w * 2 + 1;
  const int sr0 = q0 * 16 + (lane >> 2);
  const int sr1 = q1 * 16 + (lane >> 2);
  const int scol = (lane & 3) * 8;
  f32x4 acc[4][4] = {};
  const short* Ab0 = A + (size_t)(m0 + sr0) * lda + scol;
  const short* Ab1 = A + (size_t)(m0 + sr1) * lda + scol;
  const short* Bb0 = W + (size_t)(n0 + sr0) * ldb + scol;
  const short* Bb1 = W + (size_t)(n0 + sr1) * ldb + scol;
  for (int k0 = 0; k0 < K; k0 += 32) {
    gload16(Ab0 + k0, &sA[q0 * 512]);
    gload16(Ab1 + k0, &sA[q1 * 512]);
    gload16(Bb0 + k0, &sB[q0 * 512]);
    gload16(Bb1 + k0, &sB[q1 * 512]);
    __syncthreads();
    short8 af[4], bf[4];
#pragma unroll
    for (int i = 0; i < 4; i++) {
      af[i] = *(const short8*)&sA[(wm + i * 16 + fr) * 32 + fk];
      bf[i] = *(const short8*)&sB[(wn + i * 16 + fr) * 32 + fk];
    }
#pragma unroll
    for (int i = 0; i < 4; i++)
#pragma unroll
      for (int j = 0; j < 4; j++)
        acc[i][j] = __builtin_amdgcn_mfma_f32_16x16x32_bf16(af[i], bf[j], acc[i][j], 0, 0, 0);
    __syncthreads();
  }
#pragma unroll
  for (int i = 0; i < 4; i++)
#pragma unroll
    for (int j = 0; j < 4; j++)
#pragma unroll
      for (int q = 0; q < 4; q++) {
        int mm = m0 + wm + i * 16 + (lane >> 4) * 4 + q;
        int nn = n0 + wn + j * 16 + fr;
        if (mm < M) C[(size_t)mm * ldc + nn] = acc[i][j][q];
      }
}

// ---------------------------------------------------------------------------
// 64x64 bf16 GEMM, out_proj with residual accumulate: res += y @ Wout^T
// ---------------------------------------------------------------------------
__global__ __launch_bounds__(256) void k_gemm64(const short* __restrict__ A, int lda,
                                                const short* __restrict__ W, int ldb,
                                                float* __restrict__ C, int ldc,
                                                int M, int N, int K) {
  __shared__ short sA[64 * 32];
  __shared__ short sB[64 * 32];
  const int tid = threadIdx.x;
  const int lane = tid & 63, w = tid >> 6;
  const int m0 = blockIdx.x * 64, n0 = blockIdx.y * 64;
  const int wm = (w >> 1) * 32, wn = (w & 1) * 32;
  const int fr = lane & 15;
  const int fk = (lane >> 4) * 8;
  const int srow = w * 16 + (lane >> 2);
  const int scol = (lane & 3) * 8;
  f32x4 acc[2][2] = {};
  const short* Ab = A + (size_t)(m0 + srow) * lda + scol;
  const short* Bb = W + (size_t)(n0 + srow) * ldb + scol;
  for (int k0 = 0; k0 < K; k0 += 32) {
    gload16(Ab + k0, &sA[w * 512]);
    gload16(Bb + k0, &sB[w * 512]);
    __syncthreads();
    short8 af0 = *(const short8*)&sA[(wm + fr) * 32 + fk];
    short8 af1 = *(const short8*)&sA[(wm + 16 + fr) * 32 + fk];
    short8 bf0 = *(const short8*)&sB[(wn + fr) * 32 + fk];
    short8 bf1 = *(const short8*)&sB[(wn + 16 + fr) * 32 + fk];
    acc[0][0] = __builtin_amdgcn_mfma_f32_16x16x32_bf16(af0, bf0, acc[0][0], 0, 0, 0);
    acc[0][1] = __builtin_amdgcn_mfma_f32_16x16x32_bf16(af0, bf1, acc[0][1], 0, 0, 0);
    acc[1][0] = __builtin_amdgcn_mfma_f32_16x16x32_bf16(af1, bf0, acc[1][0], 0, 0, 0);
    acc[1][1] = __builtin_amdgcn_mfma_f32_16x16x32_bf16(af1, bf1, acc[1][1], 0, 0, 0);
    __syncthreads();
  }
#pragma unroll
  for (int i = 0; i < 2; i++)
#pragma unroll
    for (int j = 0; j < 2; j++)
#pragma unroll
      for (int q = 0; q < 4; q++) {
        int mm = m0 + wm + i * 16 + (lane >> 4) * 4 + q;
        int nn = n0 + wn + j * 16 + fr;
        if (mm < M) C[(size_t)mm * ldc + nn] += acc[i][j][q];
      }
}

// ---------------------------------------------------------------------------
// FUSED conv + x_proj + dt_proj with ASYNC LDS staging (unchanged from R8).
// ---------------------------------------------------------------------------
__global__ __launch_bounds__(256, 1) void k_cxd3(const float* __restrict__ xz,
                                                 const float* __restrict__ wc,
                                                 const float* __restrict__ bc,
                                                 const short* __restrict__ wx,
                                                 const short* __restrict__ wdt,
                                                 const float* __restrict__ dbias,
                                                 float* __restrict__ xc,
                                                 float* __restrict__ dbl,
                                                 float* __restrict__ dtb) {
  __shared__ float sXZ[XZROWS * 768];   // 58368 B
  __shared__ float sWC[768 * 4];        // 12288 B
  __shared__ float sBC[768];            //  3072 B
  __shared__ short sXC[16 * 776];       // 24832 B
  __shared__ short sDT[16 * 40];        //  1280 B
  const int tid = threadIdx.x;
  const int t0 = blockIdx.x * 16;
  const int lane = tid & 63, wv = tid >> 6;
  // ---- phase 0: async staging (DMA; one drain at the barrier)
  for (int r = wv; r < XZROWS; r += 4) {
    int srow = t0 - 3 + r; if (srow < 0) srow = 0;
    const float* src = xz + (size_t)srow * (2 * DI);
#pragma unroll
    for (int s = 0; s < 3; s++)
      gload16f(src + s * 256 + lane * 4, &sXZ[r * 768 + s * 256]);
  }
#pragma unroll
  for (int s = 0; s < 3; s++) {
    int off = (wv * 3 + s) * 256;
    gload16f(wc + off + lane * 4, &sWC[off]);
  }
  if (wv < 3) {
    int off = wv * 256;
    gload16f(bc + off + lane * 4, &sBC[off]);
  }
  __syncthreads();   // compiler drains vmcnt before barrier
  // ---- phase 1: conv + SiLU from LDS (16 tokens x 192 groups; 12/thread)
#pragma unroll
  for (int it = 0; it < 12; it++) {
    int g = tid + it * 256;
    int tl = g / 192, eg = g % 192;
    int e = eg * 4;
    int t = t0 + tl;
    int l = t % LL;
    const float* baseL = &sXZ[(tl + 3) * 768 + e];
    float4 w0 = *(const float4*)&sWC[(e + 0) * 4];
    float4 w1 = *(const float4*)&sWC[(e + 1) * 4];
    float4 w2 = *(const float4*)&sWC[(e + 2) * 4];
    float4 w3 = *(const float4*)&sWC[(e + 3) * 4];
    float4 acc = *(const float4*)&sBC[e];
    if (l >= 3) {
      float4 xv = *(const float4*)&baseL[-3 * 768];
      acc.x += xv.x * w0.x; acc.y += xv.y * w1.x; acc.z += xv.z * w2.x; acc.w += xv.w * w3.x;
    }
    if (l >= 2) {
      float4 xv = *(const float4*)&baseL[-2 * 768];
      acc.x += xv.x * w0.y; acc.y += xv.y * w1.y; acc.z += xv.z * w2.y; acc.w += xv.w * w3.y;
    }
    if (l >= 1) {
      float4 xv = *(const float4*)&baseL[-768];
      acc.x += xv.x * w0.z; acc.y += xv.y * w1.z; acc.z += xv.z * w2.z; acc.w += xv.w * w3.z;
    }
    {
      float4 xv = *(const float4*)&baseL[0];
      acc.x += xv.x * w0.w; acc.y += xv.y * w1.w; acc.z += xv.z * w2.w; acc.w += xv.w * w3.w;
    }
    acc.x = acc.x / (1.f + __expf(-acc.x));
    acc.y = acc.y / (1.f + __expf(-acc.y));
    acc.z = acc.z / (1.f + __expf(-acc.z));
    acc.w = acc.w / (1.f + __expf(-acc.w));
    *(float4*)&xc[(size_t)t * DI + e] = acc;
    short4v ov = {f2bf(acc.x), f2bf(acc.y), f2bf(acc.z), f2bf(acc.w)};
    *(short4v*)&sXC[tl * 776 + e] = ov;
  }
  __syncthreads();
  // ---- phase 2: x_proj (A from sXC, W from L2-hot global, no barriers)
  const int fr = lane & 15;
  const int fk = (lane >> 4) * 8;
  f32x4 acc0 = {}, acc1 = {};
  const short* Wrow = wx + (size_t)(wv * 16 + fr) * DI + fk;
#pragma unroll
  for (int k0 = 0; k0 < DI; k0 += 64) {
    short8 af0 = *(const short8*)&sXC[fr * 776 + k0 + fk];
    short8 bf0 = *(const short8*)&Wrow[k0];
    short8 af1 = *(const short8*)&sXC[fr * 776 + k0 + 32 + fk];
    short8 bf1 = *(const short8*)&Wrow[k0 + 32];
    acc0 = __builtin_amdgcn_mfma_f32_16x16x32_bf16(af0, bf0, acc0, 0, 0, 0);
    acc1 = __builtin_amdgcn_mfma_f32_16x16x32_bf16(af1, bf1, acc1, 0, 0, 0);
  }
  f32x4 accx = acc0 + acc1;
  // ---- phase 3: scatter dbl (cols 24..55) + sDT (cols 0..23, pad 0)
  {
    int nn = wv * 16 + fr;
#pragma unroll
    for (int q = 0; q < 4; q++) {
      int row = (lane >> 4) * 4 + q;
      int t = t0 + row;
      if (nn >= DTR && nn < 56) dbl[(size_t)t * 56 + nn] = accx[q];
      if (wv < 2) sDT[row * 40 + nn] = (nn < DTR) ? f2bf(accx[q]) : (short)0;
    }
  }
  __syncthreads();
  // ---- phase 4: dt_proj (M=16, N=768, K=24 pad 32), W from global
  short8 adt = *(const short8*)&sDT[fr * 40 + fk];
  const int g = lane >> 4;
#pragma unroll
  for (int jj = 0; jj < 12; jj++) {
    int j = wv * 12 + jj;
    short8 bdt = short8{0, 0, 0, 0, 0, 0, 0, 0};
    if (g < 3) bdt = *(const short8*)&wdt[(size_t)(j * 16 + fr) * DTR + g * 8];
    f32x4 p = {};
    p = __builtin_amdgcn_mfma_f32_16x16x32_bf16(adt, bdt, p, 0, 0, 0);
    int nc = j * 16 + fr;
    float bv = dbias[nc];
#pragma unroll
    for (int q = 0; q < 4; q++) {
      int t = t0 + (lane >> 4) * 4 + q;
      float v = p[q] + bv;
      v = (v > 20.f) ? v : __logf(1.f + __expf(v));
      dtb[(size_t)t * DI + nc] = v;
    }
  }
}

// ---------------------------------------------------------------------------
// SINGLE-DISPATCH chunked scan — 16 chunks x 13 tokens, 1024 threads
// (16 waves, wave = chunk). LDS carry 69.6 KB -> 2 blocks/CU = 32 waves/CU
// (occupancy cap). Serial chain 26 steps vs 34. exp-reduction (powers of
// p=exp(-dt)) with wave-uniform arange check; generic fallback preserved.
// ---------------------------------------------------------------------------
__global__ __launch_bounds__(1024) void k_scan(const float* __restrict__ dt,
                                               const float* __restrict__ xc,
                                               const float* __restrict__ xz,
                                               const float* __restrict__ dbl,
                                               const float* __restrict__ Alog,
                                               const float* __restrict__ Dp,
                                               short* __restrict__ ybf) {
  __shared__ float carry[NCHUNK][32][2][17];  // [c][e][nh][0..7 Aprod, 8..15 Hend]
  const int tid = threadIdx.x;
  const int c  = tid >> 6;          // wave index = chunk (0..15)
  const int nh = (tid >> 5) & 1;
  const int el = tid & 31;
  const int e  = blockIdx.x * 32 + el;
  const int b  = blockIdx.y;
  float4 al0 = *(const float4*)&Alog[(size_t)e * DSN + nh * 8];
  float4 al1 = *(const float4*)&Alog[(size_t)e * DSN + nh * 8 + 4];
  float negA[8] = {-__expf(al0.x), -__expf(al0.y), -__expf(al0.z), -__expf(al0.w),
                   -__expf(al1.x), -__expf(al1.y), -__expf(al1.z), -__expf(al1.w)};
  // A_log arange-structure check: negA[j] ?= -(nh*8+j+1). Wave-uniform.
  bool fa = true;
#pragma unroll
  for (int j = 0; j < 8; j++) {
    float expect = (float)(nh * 8 + j + 1);
    fa = fa && (fabsf(negA[j] + expect) <= 1e-3f * expect);
  }
  const bool fastA = __all(fa);
  const int l0 = c * CH;
  const int l1 = (l0 + CH < LL) ? (l0 + CH) : LL;
  const size_t tbase = (size_t)b * LL;
  // ---- pass 1: local chunk scan (last chunk's carry never consumed)
  if (c < NCHUNK - 1) {
    float h[8] = {};
    float asum = 0.f;
    for (int l = l0; l < l1; l++) {
      size_t t = tbase + l;
      float dtv = dt[t * DI + e];
      float xcv = xc[t * DI + e];
      float4 B0 = *(const float4*)&dbl[t * 56 + DTR + nh * 8];
      float4 B1 = *(const float4*)&dbl[t * 56 + DTR + nh * 8 + 4];
      float dA[8];
      if (fastA) {
        float p = __expf(-dtv);
        float p2 = p * p, p4 = p2 * p2;
        float cur = nh ? (p4 * p4) : 1.f;
#pragma unroll
        for (int j = 0; j < 8; j++) { cur *= p; dA[j] = cur; }
      } else {
#pragma unroll
        for (int j = 0; j < 8; j++) dA[j] = __expf(dtv * negA[j]);
      }
      float dx = dtv * xcv;
      float Bv[8] = {B0.x, B0.y, B0.z, B0.w, B1.x, B1.y, B1.z, B1.w};
#pragma unroll
      for (int j = 0; j < 8; j++)
        h[j] = dA[j] * h[j] + dx * Bv[j];
      asum += dtv;
    }
    float cA[8];
    if (fastA) {
      float p = __expf(-asum);
      float p2 = p * p, p4 = p2 * p2;
      float cur = nh ? (p4 * p4) : 1.f;
#pragma unroll
      for (int j = 0; j < 8; j++) { cur *= p; cA[j] = cur; }
    } else {
#pragma unroll
      for (int j = 0; j < 8; j++) cA[j] = __expf(asum * negA[j]);
    }
#pragma unroll
    for (int j = 0; j < 8; j++) {
      carry[c][el][nh][j]     = cA[j];
      carry[c][el][nh][8 + j] = h[j];
    }
  }
  __syncthreads();
  // ---- carry fold (cp ascending)
  float h[8] = {};
  for (int cp = 0; cp < c; cp++) {
#pragma unroll
    for (int j = 0; j < 8; j++)
      h[j] = carry[cp][el][nh][j] * h[j] + carry[cp][el][nh][8 + j];
  }
  // ---- pass 2: rescan with correct h0, gate, write y
  const float dpv = Dp[e];
  for (int l = l0; l < l1; l++) {
    size_t t = tbase + l;
    float dtv = dt[t * DI + e];
    float xcv = xc[t * DI + e];
    float zv = xz[t * (2 * DI) + DI + e];
    float4 B0 = *(const float4*)&dbl[t * 56 + DTR + nh * 8];
    float4 B1 = *(const float4*)&dbl[t * 56 + DTR + nh * 8 + 4];
    float4 C0 = *(const float4*)&dbl[t * 56 + DTR + DSN + nh * 8];
    float4 C1 = *(const float4*)&dbl[t * 56 + DTR + DSN + nh * 8 + 4];
    float dA[8];
    if (fastA) {
      float p = __expf(-dtv);
      float p2 = p * p, p4 = p2 * p2;
      float cur = nh ? (p4 * p4) : 1.f;
#pragma unroll
      for (int j = 0; j < 8; j++) { cur *= p; dA[j] = cur; }
    } else {
#pragma unroll
      for (int j = 0; j < 8; j++) dA[j] = __expf(dtv * negA[j]);
    }
    float dx = dtv * xcv;
    float Bv[8] = {B0.x, B0.y, B0.z, B0.w, B1.x, B1.y, B1.z, B1.w};
    float Cv[8] = {C0.x, C0.y, C0.z, C0.w, C1.x, C1.y, C1.z, C1.w};
    float acc = 0.f;
#pragma unroll
    for (int j = 0; j < 8; j++) {
      h[j] = dA[j] * h[j] + dx * Bv[j];
      acc += h[j] * Cv[j];
    }
    acc += __shfl_xor(acc, 32);   // nh-pair (lanes el and el+32)
    if (nh == 0) {
      float sz = zv * (1.f / (1.f + __expf(-zv)));
      ybf[t * DI + e] = f2bf((acc + xcv * dpv) * sz);
    }
  }
}

// ---------------------------------------------------------------------------
// pure LN: u = LN(res)*nw+nb (bf16). One wave per token; no barriers.
// ---------------------------------------------------------------------------
__global__ __launch_bounds__(256) void k_ln(const float* __restrict__ res,
                                            short* __restrict__ u,
                                            const float* __restrict__ nw,
                                            const float* __restrict__ nb) {
  const int lane = threadIdx.x & 63;
  const int t = blockIdx.x * 4 + (threadIdx.x >> 6);
  float r[6];
  float s = 0.f, sq = 0.f;
#pragma unroll
  for (int j = 0; j < 6; j++) {
    int d = lane + j * 64;
    float v = res[(size_t)t * DD + d];
    r[j] = v;
    s += v; sq += v * v;
  }
#pragma unroll
  for (int o = 32; o > 0; o >>= 1) { s += __shfl_xor(s, o); sq += __shfl_xor(sq, o); }
  float mu = s * (1.f / 384.f);
  float var = sq * (1.f / 384.f) - mu * mu;
  float rs = rsqrtf(var + EPSV);
#pragma unroll
  for (int j = 0; j < 6; j++) {
    int d = lane + j * 64;
    u[(size_t)t * DD + d] = f2bf((r[j] - mu) * rs * nw[d] + nb[d]);
  }
}

// ---------------------------------------------------------------------------
// final: LN(res[b,0]) -> head. grid (8, BB). (res already includes last hid)
// ---------------------------------------------------------------------------
__global__ __launch_bounds__(256) void k_final(const float* __restrict__ res,
                                               const float* __restrict__ nfw,
                                               const float* __restrict__ nfb,
                                               const float* __restrict__ hw,
                                               const float* __restrict__ hb,
                                               float* __restrict__ out) {
  const int b = blockIdx.y;
  const int c0 = blockIdx.x * 125;
  const int tid = threadIdx.x;
  __shared__ float u0[DD];
  __shared__ float ls[4], lq[4];
  const size_t t0 = (size_t)b * LL * DD;
  float v0 = res[t0 + tid];
  float v1 = (tid < 128) ? res[t0 + 256 + tid] : 0.f;
  float s = v0 + v1, sq = v0 * v0 + v1 * v1;
#pragma unroll
  for (int o = 32; o > 0; o >>= 1) { s += __shfl_xor(s, o); sq += __shfl_xor(sq, o); }
  if ((tid & 63) == 0) { ls[tid >> 6] = s; lq[tid >> 6] = sq; }
  __syncthreads();
  float st = ls[0] + ls[1] + ls[2] + ls[3];
  float qt = lq[0] + lq[1] + lq[2] + lq[3];
  float mu = st * (1.f / 384.f);
  float var = qt * (1.f / 384.f) - mu * mu;
  float rs = rsqrtf(var + EPSV);
  u0[tid] = (v0 - mu) * rs * nfw[tid] + nfb[tid];
  if (tid < 128) u0[256 + tid] = (v1 - mu) * rs * nfw[256 + tid] + nfb[256 + tid];
  __syncthreads();
  int c = c0 + tid;
  if (tid < 125 && c < NC) {
    float acc = hb[c];
    const float* wrow = hw + (size_t)c * DD;
    for (int d = 0; d < DD; d += 4) {
      float4 w4 = *(const float4*)&wrow[d];
      acc += u0[d] * w4.x + u0[d + 1] * w4.y + u0[d + 2] * w4.z + u0[d + 3] * w4.w;
    }
    out[(size_t)b * NC + c] = acc;
  }
}

// ---------------------------------------------------------------------------
extern "C" void kernel_launch(void* const* d_in, const int* in_sizes, int n_in,
                              void* d_out, int out_size, void* d_ws, size_t ws_size,
                              hipStream_t stream) {
  const float* x       = (const float*)d_in[0];
  const float* patch_w = (const float*)d_in[1];
  const float* patch_b = (const float*)d_in[2];
  const float* cls     = (const float*)d_in[3];
  const float* pos     = (const float*)d_in[4];
  const float* in_proj = (const float*)d_in[5];
  const float* conv_w  = (const float*)d_in[6];
  const float* conv_b  = (const float*)d_in[7];
  const float* x_proj  = (const float*)d_in[8];
  const float* dt_w    = (const float*)d_in[9];
  const float* dt_b    = (const float*)d_in[10];
  const float* A_log   = (const float*)d_in[11];
  const float* D_ssm   = (const float*)d_in[12];
  const float* out_w   = (const float*)d_in[13];
  const float* norm_w  = (const float*)d_in[14];
  const float* norm_b  = (const float*)d_in[15];
  const float* normf_w = (const float*)d_in[16];
  const float* normf_b = (const float*)d_in[17];
  const float* head_w  = (const float*)d_in[18];
  const float* head_b  = (const float*)d_in[19];
  float* out = (float*)d_out;

  float* ws = (float*)d_ws;
  float* res = ws;  ws += (size_t)TT * DD;        // h accumulator (init + Σ hid)
  float* u_r = ws;  ws += (size_t)TT * DD;        // u as bf16 (half used)
  float* xzb = ws;  ws += (size_t)TT * 2 * DI;
  float* xcb = ws;  ws += (size_t)TT * DI;
  float* dbl = ws;  ws += (size_t)TT * 56;
  float* dtb = ws;  ws += (size_t)TT * DI;
  float* ybf_r = ws; ws += (size_t)TT * DI / 2;   // y bf16
  // bf16 weights (converted once per call)
  short* winbf  = (short*)ws; ws += (size_t)DEPTH * 2 * DI * DD / 2;
  short* woutbf = (short*)ws; ws += (size_t)DEPTH * DD * DI / 2;
  short* wxbf   = (short*)ws; ws += (size_t)DEPTH * 56 * DI / 2;
  short* wdtbf  = (short*)ws; ws += (size_t)DEPTH * DI * DTR / 2;

  short* u    = (short*)u_r;
  short* ybf  = (short*)ybf_r;

  // one-time weight conversions, single dispatch
  {
    int n1 = DEPTH * 2 * DI * DD;   // 14.16M
    int n2 = DEPTH * DD * DI;       // 7.08M
    int n3 = DEPTH * 56 * DI;       // 1.03M
    int n4 = DEPTH * DI * DTR;      // 0.44M
    int g1 = (n1 / 4 + 255) / 256;
    int g2 = (n2 / 4 + 255) / 256;
    int g3 = (n3 / 4 + 255) / 256;
    int g4 = (n4 / 4 + 255) / 256;
    k_cvt4<<<g1 + g2 + g3 + g4, 256, 0, stream>>>(
        in_proj, winbf, n1, out_w, woutbf, n2, x_proj, wxbf, n3, dt_w, wdtbf, n4,
        g1, g1 + g2, g1 + g2 + g3);
  }

  k_init<<<(BB * DD + 255) / 256, 256, 0, stream>>>(cls, pos, res);
  k_patch<<<dim3(49, 6), 256, 0, stream>>>(x, patch_w, patch_b, pos, res);

  for (int layer = 0; layer < DEPTH; layer++) {
    // pure LN: u = LN(res)
    k_ln<<<TT / 4, 256, 0, stream>>>(res, u, norm_w + layer * DD,
                                     norm_b + layer * DD);
    // in_proj: u_bf16 (3152,384) @ Win_bf16^T (1536,384) -> xz fp32
    k_gemm128<<<dim3(25, 12), 256, 0, stream>>>(
        u, DD, winbf + (size_t)layer * 2 * DI * DD, DD, xzb, 2 * DI, TT, 2 * DI, DD);
    // fused conv + x_proj + dt_proj (async-staged)
    k_cxd3<<<dim3(TT / 16), 256, 0, stream>>>(
        xzb, conv_w + layer * DI * 4, conv_b + layer * DI,
        wxbf + (size_t)layer * 56 * DI, wdtbf + (size_t)layer * DI * DTR,
        dt_b + layer * DI, xcb, dbl, dtb);
    // single-dispatch chunked scan (16 chunks, 1024 threads, carries in LDS)
    k_scan<<<dim3(DI / 32, BB), 1024, 0, stream>>>(
        dtb, xcb, xzb, dbl, A_log + (size_t)layer * DI * DSN,
        D_ssm + layer * DI, ybf);
    // out_proj with residual accumulate: res += y @ Wout^T
    k_gemm64<<<dim3(50, 6), 256, 0, stream>>>(
        ybf, DI, woutbf + (size_t)layer * DD * DI, DI, res, DD, TT, DD, DI);
  }

  k_final<<<dim3(8, BB), 256, 0, stream>>>(res, normf_w, normf_b, head_w, head_b, out);
}